// Round 6
// baseline (4006.753 us; speedup 1.0000x reference)
//
#include <hip/hip_runtime.h>
#include <hip/hip_bf16.h>
#include <math.h>

// InformationPlane R6:
// - gemm2: 64x64 lower-tri tiles (576 blocks, 256thr, 40KB LDS -> 4 blk/CU
//   capacity), depth-2 register prefetch, 1 barrier/K-step.
// - k_eigen fast path: NO matrix read. Diags are exact constants by
//   construction (d2 diag forced 0 -> exp(0)=1 -> 1/512; joints 2^-18; all
//   powers of two). off2 fused into producers: Ay from ||Ky||F^2 (k_ky),
//   Ax from gemm mode1 (sum ax^2), A/AxA/AAy from k_aj (fp64 sums).
//   Jacobi fallback (reads matrix) kept for off2*scale^2 > 1e-8.
// - atomic decongestion: k_ky 256 blk/batch, k_aj 128 blk/batch, block-level
//   reduction before atomics; k_loss float4 loads.

#define NBATCH 8
#define MBS    512
#define DXX    8192
#define DII    3072
#define NSIG   50
#define NN     262144                 // 512*512
#define NTOT   ((size_t)33554432)     // 4096*8192

// scal (double) indices
#define I_SUMD  0    // 8
#define I_KYF   8    // 8
#define I_SIGMA 24   // 8
#define I_ENT   32   // 40 (b*5+m)
#define I_NUM   96   // 8*50
#define I_DEN   512  // 8*50 -> 912
#define I_AX2   912  // 8  sum ax^2 (full matrix)
#define I_A2    920  // 8  sum a^2
#define I_JX2   928  // 8  sum (ax*a)^2
#define I_JY2   936  // 8  sum (a*ay)^2  -> ends 944

typedef __attribute__((ext_vector_type(8))) short bf16x8;
typedef __attribute__((ext_vector_type(4))) float f32x4;

__device__ __forceinline__ size_t slotOf(int b, int m) {
  return ((size_t)(b * 5 + m)) * (size_t)NN;
}

__device__ __forceinline__ short f2b(float f) {
  __hip_bfloat16 h = __float2bfloat16(f);   // pairs fuse to v_cvt_pk_bf16_f32
  return *(short*)&h;
}

// ---------------- copy x -> out (small-ws path only) ----------------
__global__ void k_copy(const float4* __restrict__ src, float4* __restrict__ dst, size_t n4) {
  size_t i = (size_t)blockIdx.x * blockDim.x + threadIdx.x;
  size_t stride = (size_t)gridDim.x * blockDim.x;
  for (; i < n4; i += stride) dst[i] = src[i];
}

// ---------------- x: norm + bf16 convert (+ optional out-copy) ----------------
template <int COPY>
__global__ void k_prep_x(const float4* __restrict__ src, float4* __restrict__ dst,
                         ushort* __restrict__ xbf, float* __restrict__ nrm) {
  int row = blockIdx.x, t = threadIdx.x;
  const float4* p = src + (size_t)row * 2048;
  bf16x8* o = (bf16x8*)(xbf + (size_t)row * 8192);
  double s = 0.0;
#pragma unroll
  for (int l = 0; l < 4; l++) {
    int i = t + l * 256;                 // ushort8 index 0..1023
    float4 a = p[2 * i], c = p[2 * i + 1];
    if (COPY) { float4* q = dst + (size_t)row * 2048; q[2 * i] = a; q[2 * i + 1] = c; }
    bf16x8 v;
    v[0] = f2b(a.x); v[1] = f2b(a.y); v[2] = f2b(a.z); v[3] = f2b(a.w);
    v[4] = f2b(c.x); v[5] = f2b(c.y); v[6] = f2b(c.z); v[7] = f2b(c.w);
    o[i] = v;
    s += (double)a.x * a.x + (double)a.y * a.y + (double)a.z * a.z + (double)a.w * a.w;
    s += (double)c.x * c.x + (double)c.y * c.y + (double)c.z * c.z + (double)c.w * c.w;
  }
  __shared__ double red[256];
  red[t] = s; __syncthreads();
  for (int o2 = 128; o2 > 0; o2 >>= 1) {
    if (t < o2) red[t] += red[t + o2];
    __syncthreads();
  }
  if (t == 0) nrm[row] = (float)red[0];
}

// ---------------- inp: norm + bf16 convert ----------------
__global__ void k_prep_i(const float* __restrict__ src, ushort* __restrict__ ibf,
                         float* __restrict__ nrm) {
  int row = blockIdx.x, t = threadIdx.x;     // t < 384
  const float4* p = (const float4*)(src + (size_t)row * 3072);
  bf16x8* o = (bf16x8*)(ibf + (size_t)row * 3072);
  float4 a = p[2 * t], c = p[2 * t + 1];
  bf16x8 v;
  v[0] = f2b(a.x); v[1] = f2b(a.y); v[2] = f2b(a.z); v[3] = f2b(a.w);
  v[4] = f2b(c.x); v[5] = f2b(c.y); v[6] = f2b(c.z); v[7] = f2b(c.w);
  o[t] = v;
  double s = (double)a.x * a.x + (double)a.y * a.y + (double)a.z * a.z + (double)a.w * a.w
           + (double)c.x * c.x + (double)c.y * c.y + (double)c.z * c.z + (double)c.w * c.w;
  for (int off = 32; off > 0; off >>= 1) s += __shfl_down(s, off, 64);
  __shared__ double wred[6];
  if ((t & 63) == 0) wred[t >> 6] = s;
  __syncthreads();
  if (t == 0) {
    double tt = 0.0;
#pragma unroll
    for (int w = 0; w < 6; w++) tt += wred[w];
    nrm[row] = (float)tt;
  }
}

// ---------------- label kernel Ky (-> Ay slot), ||Ky||_F^2 ----------------
// grid (256, 8), 4 elems/thread, one fp64 atomic per block.
__global__ __launch_bounds__(256) void k_ky(const float* __restrict__ lab,
                                            float* __restrict__ eig,
                                            double* __restrict__ scal) {
  int b = blockIdx.y;
  int e0 = blockIdx.x * 1024 + threadIdx.x * 4;
  int i = e0 >> 9;
  const float* L = lab + (size_t)b * MBS * 10;
  float4 out;
  double s = 0.0;
#pragma unroll
  for (int u = 0; u < 4; u++) {
    int j = (e0 & 511) + u;
    float d2 = 0.0f;
#pragma unroll
    for (int d = 0; d < 10; d++) { float t = L[i * 10 + d] - L[j * 10 + d]; d2 += t * t; }
    float ky = __expf(-d2 * 100.0f);
    ((float*)&out)[u] = ky * (1.0f / 512.0f);
    s += (double)ky * ky;
  }
  *(float4*)&eig[slotOf(b, 2) + e0] = out;
  __shared__ double red[256];
  red[threadIdx.x] = s; __syncthreads();
  for (int o = 128; o > 0; o >>= 1) {
    if (threadIdx.x < o) red[threadIdx.x] += red[threadIdx.x + o];
    __syncthreads();
  }
  if (threadIdx.x == 0) atomicAdd(&scal[I_KYF + b], red[0]);
}

// ---------------- symmetric bf16-MFMA pdist2 GEMM, 64x64 tiles ----------------
// grid 576: id%8 = batch (XCD-grouped); tm = id>>3: tm<36 -> mode0 (x, D=8192,
// d2 -> slot(b,1) + fused sqrt-sum/count), else mode1 (inp, D=3072,
// Ax=exp(-d2/64)/512 -> slot(b,0) + fused sum ax^2).
// 64x64 lower-tri tile, BK=64, 256 thr (4 waves 2x2, wave tile 32x32).
// Depth-2 register prefetch + double-buffered LDS, 1 barrier/K-step.
#define LSTR 72   // ushorts per LDS row
__global__ __launch_bounds__(256) void k_gemm2(
    const ushort* __restrict__ xbf, const ushort* __restrict__ inpbf,
    const float* __restrict__ nrmx, const float* __restrict__ nrmi,
    float* __restrict__ eig, double* __restrict__ scal,
    unsigned long long* __restrict__ cnt)
{
  int id = blockIdx.x;
  int b = id & 7;
  int tm = id >> 3;                 // 0..71
  int mode = (tm >= 36) ? 1 : 0;
  int t = tm - mode * 36;           // 0..35 lower-triangle tile
  int bx = 0;
#pragma unroll
  for (int r = 1; r < 8; r++) if (t >= (r * (r + 1)) / 2) bx = r;
  int by = t - (bx * (bx + 1)) / 2;
  bool diag = (bx == by);
  int D = mode ? DII : DXX;
  const ushort* src = (mode ? inpbf : xbf) + (size_t)b * MBS * D;
  const float* nb = (mode ? nrmi : nrmx) + b * MBS;
  int row0 = bx * 64, col0 = by * 64;

  __shared__ ushort As[2][64 * LSTR];
  __shared__ ushort Bs[2][64 * LSTR];
  __shared__ double redd[256];
  __shared__ unsigned redi[256];

  int tid = threadIdx.x;
  int lane = tid & 63, w = tid >> 6;
  int wr = (w >> 1) * 32, wc = (w & 1) * 32;
  int l15 = lane & 15, l4 = lane >> 4;

  f32x4 acc[2][2];
#pragma unroll
  for (int m = 0; m < 2; m++)
#pragma unroll
    for (int n = 0; n < 2; n++) {
      acc[m][n][0] = 0.f; acc[m][n][1] = 0.f; acc[m][n][2] = 0.f; acc[m][n][3] = 0.f;
    }

  int rr = tid >> 3;            // 0..31
  int cc = (tid & 7) * 8;       // 0..56

  bf16x8 pa[2][2], pb[2][2];
  auto loadk = [&](int d, int k0) {
    pa[d][0] = *(const bf16x8*)&src[(size_t)(row0 + rr) * D + k0 + cc];
    pa[d][1] = *(const bf16x8*)&src[(size_t)(row0 + 32 + rr) * D + k0 + cc];
    if (!diag) {
      pb[d][0] = *(const bf16x8*)&src[(size_t)(col0 + rr) * D + k0 + cc];
      pb[d][1] = *(const bf16x8*)&src[(size_t)(col0 + 32 + rr) * D + k0 + cc];
    }
  };

  loadk(0, 0);
  loadk(1, 64);
  int nk = D >> 6;
  for (int k = 0; k < nk; k++) {
    int buf = k & 1;
    *(bf16x8*)&As[buf][rr * LSTR + cc] = pa[buf][0];
    *(bf16x8*)&As[buf][(32 + rr) * LSTR + cc] = pa[buf][1];
    if (!diag) {
      *(bf16x8*)&Bs[buf][rr * LSTR + cc] = pb[buf][0];
      *(bf16x8*)&Bs[buf][(32 + rr) * LSTR + cc] = pb[buf][1];
    }
    __syncthreads();
    if (k + 2 < nk) loadk(buf, (k + 2) << 6);   // 2-deep: in flight across 2 steps
    const ushort* Bsrc = diag ? As[buf] : Bs[buf];
#pragma unroll
    for (int ks = 0; ks < 2; ks++) {
      bf16x8 af[2], bfr[2];
#pragma unroll
      for (int m = 0; m < 2; m++)
        af[m] = *(const bf16x8*)&As[buf][(wr + m * 16 + l15) * LSTR + ks * 32 + l4 * 8];
#pragma unroll
      for (int n = 0; n < 2; n++)
        bfr[n] = *(const bf16x8*)&Bsrc[(wc + n * 16 + l15) * LSTR + ks * 32 + l4 * 8];
#pragma unroll
      for (int m = 0; m < 2; m++)
#pragma unroll
        for (int n = 0; n < 2; n++)
          acc[m][n] = __builtin_amdgcn_mfma_f32_16x16x32_bf16(af[m], bfr[n], acc[m][n], 0, 0, 0);
    }
    // single barrier per K-step: WAR-safe across alternating buffers
  }

  // epilogue (C/D layout: col=lane&15, row=(lane>>4)*4+v); mirror off-diag
  float* dst = eig + slotOf(b, mode ? 0 : 1);
  double lsum = 0.0; unsigned lcnt = 0;
#pragma unroll
  for (int m = 0; m < 2; m++) {
    int gr = row0 + wr + m * 16 + l4 * 4;
#pragma unroll
    for (int n = 0; n < 2; n++) {
      int gc = col0 + wc + n * 16 + l15;
      float nj = nb[gc];
#pragma unroll
      for (int v = 0; v < 4; v++) {
        int gi = gr + v;
        float d2 = nb[gi] + nj - 2.0f * acc[m][n][v];
        d2 = fmaxf(d2, 0.0f);
        if (gi == gc) d2 = 0.0f;
        float val;
        if (mode == 0) {
          val = d2;
          if (d2 > 0.0f) { lsum += (double)sqrtf(d2); lcnt++; }
        } else {
          val = __expf(-d2 * (1.0f / 64.0f)) * (1.0f / 512.0f);
          lsum += (double)val * val;      // sum ax^2 (off2 fusion)
        }
        dst[(size_t)gi * MBS + gc] = val;
        if (!diag) dst[(size_t)gc * MBS + gi] = val;
      }
    }
  }
  if (!diag) { lsum *= 2.0; lcnt *= 2; }
  __syncthreads();
  redd[tid] = lsum; redi[tid] = lcnt; __syncthreads();
  for (int o = 128; o > 0; o >>= 1) {
    if (tid < o) { redd[tid] += redd[tid + o]; redi[tid] += redi[tid + o]; }
    __syncthreads();
  }
  if (tid == 0) {
    if (mode == 0) {
      atomicAdd(&scal[I_SUMD + b], redd[0]);
      atomicAdd(&cnt[b], (unsigned long long)redi[0]);
    } else {
      atomicAdd(&scal[I_AX2 + b], redd[0]);
    }
  }
}

// ---------------- sigma-search sums: 10 sigmas per block, float4 loads ----------------
__global__ __launch_bounds__(256) void k_loss(const float* __restrict__ eig,
                                              double* __restrict__ scal,
                                              const unsigned long long* __restrict__ cnt) {
  int b = blockIdx.z, g = blockIdx.y;
  double c = (double)cnt[b]; if (c < 1.0) c = 1.0;
  float md = (float)(scal[I_SUMD + b] / c);
  const float4* d2p = (const float4*)(eig + slotOf(b, 1));
  const float4* ayp = (const float4*)(eig + slotOf(b, 2));
  float inv[10];
  double ln[10], ld[10];
#pragma unroll
  for (int i = 0; i < 10; i++) {
    float sg = md * (0.1f + 0.198f * (float)(g * 10 + i));
    inv[i] = 1.0f / (sg * sg);
    ln[i] = 0.0; ld[i] = 0.0;
  }
  int base = blockIdx.x * 4096 + threadIdx.x;   // float4 units; grid.x = 16
  for (int l = 0; l < 16; l++) {
    float4 d2v = d2p[base + l * 256];
    float4 kyv = ayp[base + l * 256];
#pragma unroll
    for (int u = 0; u < 4; u++) {
      float d2 = ((const float*)&d2v)[u];
      float ky = ((const float*)&kyv)[u] * 512.0f;
#pragma unroll
      for (int i = 0; i < 10; i++) {
        float kk = __expf(-d2 * inv[i]);
        ln[i] += (double)(kk * ky);
        ld[i] += (double)(kk * kk);
      }
    }
  }
#pragma unroll
  for (int i = 0; i < 10; i++) {
    double a = ln[i], d = ld[i];
    for (int o = 32; o > 0; o >>= 1) {
      a += __shfl_down(a, o, 64);
      d += __shfl_down(d, o, 64);
    }
    if ((threadIdx.x & 63) == 0) {
      atomicAdd(&scal[I_NUM + b * NSIG + g * 10 + i], a);
      atomicAdd(&scal[I_DEN + b * NSIG + g * 10 + i], d);
    }
  }
}

// ---------------- argmax + EMA sigma chain ----------------
__global__ void k_sigma(double* __restrict__ scal, const unsigned long long* __restrict__ cnt) {
  if (threadIdx.x == 0) {
    double sigma = 0.0;
    for (int b = 0; b < NBATCH; b++) {
      double c = (double)cnt[b]; if (c < 1.0) c = 1.0;
      double md = scal[I_SUMD + b] / c;
      double kyf = sqrt(scal[I_KYF + b]);
      double best = -1.0; int bi = 0;
      for (int s = 0; s < NSIG; s++) {
        double num = scal[I_NUM + b * NSIG + s];
        double den = sqrt(scal[I_DEN + b * NSIG + s]) * kyf;
        double loss = num / den;
        if (loss > best) { best = loss; bi = s; }
      }
      double st = md * (0.1 + 0.198 * (double)bi);
      sigma = (b == 0) ? st : 0.5 * sigma + 0.5 * st;
      scal[I_SIGMA + b] = sigma;
    }
  }
}

// ---------------- A build + Schur products + off2 fusion ----------------
// grid (128, 8): 8 elems/thread; accumulates sum a^2, (ax*a)^2, (a*ay)^2.
__global__ __launch_bounds__(256) void k_aj(float* __restrict__ eig,
                                            double* __restrict__ scal) {
  int b = blockIdx.y;
  float sg = (float)scal[I_SIGMA + b];
  float inv = 1.0f / (sg * sg);
  float* A        = eig + slotOf(b, 1);
  const float* AX = eig + slotOf(b, 0);
  const float* AY = eig + slotOf(b, 2);
  float* J1       = eig + slotOf(b, 3);
  float* J2       = eig + slotOf(b, 4);
  double s1 = 0.0, s2 = 0.0, s3 = 0.0;
  size_t base = (size_t)blockIdx.x * 2048 + (size_t)threadIdx.x * 8;
#pragma unroll
  for (int h = 0; h < 2; h++) {
    size_t e = base + h * 4;
    float4 d2v = *(float4*)&A[e];
    float4 axv = *(const float4*)&AX[e];
    float4 ayv = *(const float4*)&AY[e];
    float4 av, j1v, j2v;
#pragma unroll
    for (int u = 0; u < 4; u++) {
      float a = __expf(-((const float*)&d2v)[u] * inv) * (1.0f / 512.0f);
      float j1 = ((const float*)&axv)[u] * a;
      float j2 = a * ((const float*)&ayv)[u];
      ((float*)&av)[u] = a; ((float*)&j1v)[u] = j1; ((float*)&j2v)[u] = j2;
      s1 += (double)a * a; s2 += (double)j1 * j1; s3 += (double)j2 * j2;
    }
    *(float4*)&A[e] = av;
    *(float4*)&J1[e] = j1v;
    *(float4*)&J2[e] = j2v;
  }
  __shared__ double r1[256], r2[256], r3[256];
  r1[threadIdx.x] = s1; r2[threadIdx.x] = s2; r3[threadIdx.x] = s3;
  __syncthreads();
  for (int o = 128; o > 0; o >>= 1) {
    if (threadIdx.x < o) {
      r1[threadIdx.x] += r1[threadIdx.x + o];
      r2[threadIdx.x] += r2[threadIdx.x + o];
      r3[threadIdx.x] += r3[threadIdx.x + o];
    }
    __syncthreads();
  }
  if (threadIdx.x == 0) {
    atomicAdd(&scal[I_A2 + b], r1[0]);
    atomicAdd(&scal[I_JX2 + b], r2[0]);
    atomicAdd(&scal[I_JY2 + b], r3[0]);
  }
}

// ---------------- entropies: closed-form fast path, Jacobi fallback ----------------
// Fast path: diag entries are exact constants by construction (see header);
// off2 comes from the fused accumulators -> no matrix read at all.
__global__ __launch_bounds__(512) void k_eigen(float* __restrict__ eig, double* __restrict__ scal) {
  int blk = blockIdx.x; int b = blk / 5, m = blk % 5;
  // off-diagonal Frobenius^2 from fused sums (exact: diag parts are powers of 2)
  double off2, scale0;
  if (m == 0)      { off2 = scal[I_AX2 + b] - (1.0 / 512.0);              scale0 = 1.0; }
  else if (m == 1) { off2 = scal[I_A2 + b]  - (1.0 / 512.0);              scale0 = 1.0; }
  else if (m == 2) { off2 = (scal[I_KYF + b] - 512.0) * (1.0 / 262144.0); scale0 = 1.0; }
  else if (m == 3) { off2 = scal[I_JX2 + b] - 7.450580596923828125e-9;    scale0 = 512.0; }
  else             { off2 = scal[I_JY2 + b] - 7.450580596923828125e-9;    scale0 = 512.0; }

  if (off2 * scale0 * scale0 <= 1e-8) {   // entropy err ~739*off2: negligible
    if (threadIdx.x == 0) {
      double diagv = (m >= 3) ? (1.0 / 262144.0) : (1.0 / 512.0);
      double wv = diagv * scale0 + 1e-6;
      scal[I_ENT + b * 5 + m] = -512.0 * wv * log2(wv);
    }
    return;
  }

  // ---- Jacobi fallback (reads the materialized matrix) ----
  float* M = eig + slotOf(b, m);
  int t = threadIdx.x;
  __shared__ double red[512];
  __shared__ float csA[256], csB[256];
  __shared__ int anyrot;
  __shared__ double sh_scale, sh_off2;

  red[t] = (double)M[(size_t)t * 513]; __syncthreads();
  for (int o = 256; o > 0; o >>= 1) { if (t < o) red[t] += red[t + o]; __syncthreads(); }
  if (t == 0) { double trace = red[0]; sh_scale = (m >= 3) ? 1.0 / trace : 1.0; }
  __syncthreads();
  double scale = sh_scale;

  for (int sweep = 0; sweep < 30; sweep++) {
    double c2 = 0.0;
    for (int i = 0; i < 512; i++) {
      if (i != t) { float v = M[(size_t)i * 512 + t]; c2 += (double)v * v; }
    }
    red[t] = c2; __syncthreads();
    for (int o = 256; o > 0; o >>= 1) { if (t < o) red[t] += red[t + o]; __syncthreads(); }
    if (t == 0) sh_off2 = red[0];
    __syncthreads();
    if (sh_off2 * scale * scale <= 1e-8) break;

    for (int r = 0; r < 511; r++) {
      if (t == 0) anyrot = 0;
      __syncthreads();
      if (t < 256) {
        int p, q;
        if (t == 0) { p = 511; q = r; }
        else { p = (r + t) % 511; q = (r + 511 - t) % 511; }
        float app = M[(size_t)p * 512 + p];
        float aqq = M[(size_t)q * 512 + q];
        float apq = M[(size_t)p * 512 + q];
        float c = 1.0f, sr = 0.0f;
        if (fabsf(apq) > 1e-12f) {
          float th = (aqq - app) / (2.0f * apq);
          float tt = ((th >= 0.0f) ? 1.0f : -1.0f) / (fabsf(th) + sqrtf(1.0f + th * th));
          c = 1.0f / sqrtf(1.0f + tt * tt);
          sr = tt * c;
          anyrot = 1;
        }
        csA[t] = c; csB[t] = sr;
      }
      __syncthreads();
      if (anyrot) {
        int pair = t >> 1, half = t & 1;
        float c = csA[pair], sr = csB[pair];
        int p, q;
        if (pair == 0) { p = 511; q = r; }
        else { p = (r + pair) % 511; q = (r + 511 - pair) % 511; }
        if (sr != 0.0f) {
          size_t rp = (size_t)p * 512, rq = (size_t)q * 512;
          int j0 = half * 256;
          for (int j = j0; j < j0 + 256; j++) {
            float xx = M[rp + j], yy = M[rq + j];
            M[rp + j] = c * xx - sr * yy;
            M[rq + j] = sr * xx + c * yy;
          }
        }
        __syncthreads();
        if (sr != 0.0f) {
          int j0 = half * 256;
          for (int j = j0; j < j0 + 256; j++) {
            float xx = M[(size_t)j * 512 + p], yy = M[(size_t)j * 512 + q];
            M[(size_t)j * 512 + p] = c * xx - sr * yy;
            M[(size_t)j * 512 + q] = sr * xx + c * yy;
          }
        }
      }
      __syncthreads();
    }
  }

  double wv = (double)M[(size_t)t * 513] * scale + 1e-6;
  red[t] = -wv * log2(wv); __syncthreads();
  for (int o = 256; o > 0; o >>= 1) { if (t < o) red[t] += red[t + o]; __syncthreads(); }
  if (t == 0) scal[I_ENT + b * 5 + m] = red[0];
}

// ---------------- finalize MI means ----------------
__global__ void k_final(const double* __restrict__ scal, float* __restrict__ out) {
  if (threadIdx.x == 0) {
    double ixt = 0.0, ity = 0.0;
    for (int b = 0; b < NBATCH; b++) {
      const double* E = &scal[I_ENT + b * 5];
      ixt += E[0] + E[1] - E[3];
      ity += E[1] + E[2] - E[4];
    }
    out[NTOT]     = (float)(ixt / 8.0);
    out[NTOT + 1] = (float)(ity / 8.0);
  }
}

extern "C" void kernel_launch(void* const* d_in, const int* in_sizes, int n_in,
                              void* d_out, int out_size, void* d_ws, size_t ws_size,
                              hipStream_t stream) {
  const float* x   = (const float*)d_in[0];
  const float* inp = (const float*)d_in[1];
  const float* lab = (const float*)d_in[2];
  float* out = (float*)d_out;

  char* ws = (char*)d_ws;
  double* scal = (double*)ws;                                  // 944 doubles = 7552 B
  unsigned long long* cnt = (unsigned long long*)(ws + 7552);  // 64 B -> 7616
  float* nrmx = (float*)(ws + 7680);                           // 16 KB
  float* nrmi = (float*)(ws + 24064);                          // 16 KB -> 40448

  // Scratch: eig(40MB) + xbf(64MB) + inpbf(24MB) = 134217728 B exactly.
  const size_t EIG_OFF = 65536;
  bool big = ws_size >= EIG_OFF + 134217728ULL;
  char* base = big ? (ws + EIG_OFF) : (char*)d_out;
  float* eig = (float*)base;
  ushort* xbf = (ushort*)(base + 41943040);       // 40*NN*4
  ushort* inpbf = (ushort*)(base + 109051904);    // +4096*8192*2

  hipMemsetAsync(ws, 0, 7616, stream);

  if (big) k_prep_x<1><<<4096, 256, 0, stream>>>((const float4*)x, (float4*)d_out, xbf, nrmx);
  else     k_prep_x<0><<<4096, 256, 0, stream>>>((const float4*)x, nullptr, xbf, nrmx);
  k_prep_i<<<4096, 384, 0, stream>>>(inp, inpbf, nrmi);
  k_ky<<<dim3(256, NBATCH), 256, 0, stream>>>(lab, eig, scal);
  k_gemm2<<<576, 256, 0, stream>>>(xbf, inpbf, nrmx, nrmi, eig, scal, cnt);
  k_loss<<<dim3(16, 5, NBATCH), 256, 0, stream>>>(eig, scal, cnt);
  k_sigma<<<1, 64, 0, stream>>>(scal, cnt);
  k_aj<<<dim3(128, NBATCH), 256, 0, stream>>>(eig, scal);
  k_eigen<<<40, 512, 0, stream>>>(eig, scal);
  k_final<<<1, 64, 0, stream>>>(scal, out);
  if (!big) {
    k_copy<<<2048, 256, 0, stream>>>((const float4*)x, (float4*)d_out, NTOT / 4);
  }
}

// Round 7
// 341.360 us; speedup vs baseline: 11.7376x; 11.7376x over previous
//
#include <hip/hip_runtime.h>
#include <hip/hip_bf16.h>
#include <math.h>

// InformationPlane R7: R6 structure with the gemm2 scratch-spill bug fixed.
// R6's loadk(d,...) indexed pa[d] with a RUNTIME buffer index -> ext_vector
// arrays went to scratch (localMem), 31x slowdown (rule #20). R7 unrolls the
// 2-deep pipeline with STATIC register names: even K-steps use pa*/buf0, odd
// use qa*/buf1; acc and fragments are individually named; macros keep all
// indices compile-time. 64x64 lower-tri tiles, 576 blocks, 1 barrier/K-step.
// k_eigen closed-form fast path (off2 fused into producers), Jacobi fallback.

#define NBATCH 8
#define MBS    512
#define DXX    8192
#define DII    3072
#define NSIG   50
#define NN     262144                 // 512*512
#define NTOT   ((size_t)33554432)     // 4096*8192

// scal (double) indices
#define I_SUMD  0    // 8
#define I_KYF   8    // 8
#define I_SIGMA 24   // 8
#define I_ENT   32   // 40 (b*5+m)
#define I_NUM   96   // 8*50
#define I_DEN   512  // 8*50 -> 912
#define I_AX2   912  // 8  sum ax^2
#define I_A2    920  // 8  sum a^2
#define I_JX2   928  // 8  sum (ax*a)^2
#define I_JY2   936  // 8  sum (a*ay)^2 -> ends 944

typedef __attribute__((ext_vector_type(8))) short bf16x8;
typedef __attribute__((ext_vector_type(4))) float f32x4;

__device__ __forceinline__ size_t slotOf(int b, int m) {
  return ((size_t)(b * 5 + m)) * (size_t)NN;
}

__device__ __forceinline__ short f2b(float f) {
  __hip_bfloat16 h = __float2bfloat16(f);
  return *(short*)&h;
}

// ---------------- copy x -> out (small-ws path only) ----------------
__global__ void k_copy(const float4* __restrict__ src, float4* __restrict__ dst, size_t n4) {
  size_t i = (size_t)blockIdx.x * blockDim.x + threadIdx.x;
  size_t stride = (size_t)gridDim.x * blockDim.x;
  for (; i < n4; i += stride) dst[i] = src[i];
}

// ---------------- x: norm + bf16 convert (+ optional out-copy) ----------------
template <int COPY>
__global__ void k_prep_x(const float4* __restrict__ src, float4* __restrict__ dst,
                         ushort* __restrict__ xbf, float* __restrict__ nrm) {
  int row = blockIdx.x, t = threadIdx.x;
  const float4* p = src + (size_t)row * 2048;
  bf16x8* o = (bf16x8*)(xbf + (size_t)row * 8192);
  double s = 0.0;
#pragma unroll
  for (int l = 0; l < 4; l++) {
    int i = t + l * 256;
    float4 a = p[2 * i], c = p[2 * i + 1];
    if (COPY) { float4* q = dst + (size_t)row * 2048; q[2 * i] = a; q[2 * i + 1] = c; }
    bf16x8 v;
    v[0] = f2b(a.x); v[1] = f2b(a.y); v[2] = f2b(a.z); v[3] = f2b(a.w);
    v[4] = f2b(c.x); v[5] = f2b(c.y); v[6] = f2b(c.z); v[7] = f2b(c.w);
    o[i] = v;
    s += (double)a.x * a.x + (double)a.y * a.y + (double)a.z * a.z + (double)a.w * a.w;
    s += (double)c.x * c.x + (double)c.y * c.y + (double)c.z * c.z + (double)c.w * c.w;
  }
  __shared__ double red[256];
  red[t] = s; __syncthreads();
  for (int o2 = 128; o2 > 0; o2 >>= 1) {
    if (t < o2) red[t] += red[t + o2];
    __syncthreads();
  }
  if (t == 0) nrm[row] = (float)red[0];
}

// ---------------- inp: norm + bf16 convert ----------------
__global__ void k_prep_i(const float* __restrict__ src, ushort* __restrict__ ibf,
                         float* __restrict__ nrm) {
  int row = blockIdx.x, t = threadIdx.x;     // t < 384
  const float4* p = (const float4*)(src + (size_t)row * 3072);
  bf16x8* o = (bf16x8*)(ibf + (size_t)row * 3072);
  float4 a = p[2 * t], c = p[2 * t + 1];
  bf16x8 v;
  v[0] = f2b(a.x); v[1] = f2b(a.y); v[2] = f2b(a.z); v[3] = f2b(a.w);
  v[4] = f2b(c.x); v[5] = f2b(c.y); v[6] = f2b(c.z); v[7] = f2b(c.w);
  o[t] = v;
  double s = (double)a.x * a.x + (double)a.y * a.y + (double)a.z * a.z + (double)a.w * a.w
           + (double)c.x * c.x + (double)c.y * c.y + (double)c.z * c.z + (double)c.w * c.w;
  for (int off = 32; off > 0; off >>= 1) s += __shfl_down(s, off, 64);
  __shared__ double wred[6];
  if ((t & 63) == 0) wred[t >> 6] = s;
  __syncthreads();
  if (t == 0) {
    double tt = 0.0;
#pragma unroll
    for (int w = 0; w < 6; w++) tt += wred[w];
    nrm[row] = (float)tt;
  }
}

// ---------------- label kernel Ky (-> Ay slot), ||Ky||_F^2 ----------------
__global__ __launch_bounds__(256) void k_ky(const float* __restrict__ lab,
                                            float* __restrict__ eig,
                                            double* __restrict__ scal) {
  int b = blockIdx.y;
  int e0 = blockIdx.x * 1024 + threadIdx.x * 4;
  int i = e0 >> 9;
  const float* L = lab + (size_t)b * MBS * 10;
  float4 out;
  double s = 0.0;
#pragma unroll
  for (int u = 0; u < 4; u++) {
    int j = (e0 & 511) + u;
    float d2 = 0.0f;
#pragma unroll
    for (int d = 0; d < 10; d++) { float t = L[i * 10 + d] - L[j * 10 + d]; d2 += t * t; }
    float ky = __expf(-d2 * 100.0f);
    ((float*)&out)[u] = ky * (1.0f / 512.0f);
    s += (double)ky * ky;
  }
  *(float4*)&eig[slotOf(b, 2) + e0] = out;
  __shared__ double red[256];
  red[threadIdx.x] = s; __syncthreads();
  for (int o = 128; o > 0; o >>= 1) {
    if (threadIdx.x < o) red[threadIdx.x] += red[threadIdx.x + o];
    __syncthreads();
  }
  if (threadIdx.x == 0) atomicAdd(&scal[I_KYF + b], red[0]);
}

// ---------------- symmetric bf16-MFMA pdist2 GEMM, 64x64 tiles ----------------
// 576 blocks: id%8 = batch; tm<36 -> mode0 (x), else mode1 (inp).
// Static 2-deep pipeline: even K-steps (pa*) -> LDS buf0, odd (qa*) -> buf1.
#define LSTR 72
#define LOAD_SET(A0, A1, B0, B1, K0)                                          \
  do {                                                                        \
    A0 = *(const bf16x8*)&srcA0[K0];                                          \
    A1 = *(const bf16x8*)&srcA1[K0];                                          \
    if (!diag) {                                                              \
      B0 = *(const bf16x8*)&srcB0[K0];                                        \
      B1 = *(const bf16x8*)&srcB1[K0];                                        \
    }                                                                         \
  } while (0)

#define WRITE_LDS(BUF, A0, A1, B0, B1)                                        \
  do {                                                                        \
    *(bf16x8*)&As[BUF][rr * LSTR + cc] = A0;                                  \
    *(bf16x8*)&As[BUF][(32 + rr) * LSTR + cc] = A1;                           \
    if (!diag) {                                                              \
      *(bf16x8*)&Bs[BUF][rr * LSTR + cc] = B0;                                \
      *(bf16x8*)&Bs[BUF][(32 + rr) * LSTR + cc] = B1;                         \
    }                                                                         \
  } while (0)

#define MFMA_PHASE(BUF)                                                       \
  do {                                                                        \
    const ushort* Bsrc = diag ? As[BUF] : Bs[BUF];                            \
    _Pragma("unroll")                                                         \
    for (int ks = 0; ks < 2; ks++) {                                          \
      bf16x8 af0 = *(const bf16x8*)&As[BUF][(wr + l15) * LSTR + ks * 32 + l4 * 8];      \
      bf16x8 af1 = *(const bf16x8*)&As[BUF][(wr + 16 + l15) * LSTR + ks * 32 + l4 * 8]; \
      bf16x8 bg0 = *(const bf16x8*)&Bsrc[(wc + l15) * LSTR + ks * 32 + l4 * 8];         \
      bf16x8 bg1 = *(const bf16x8*)&Bsrc[(wc + 16 + l15) * LSTR + ks * 32 + l4 * 8];    \
      acc00 = __builtin_amdgcn_mfma_f32_16x16x32_bf16(af0, bg0, acc00, 0, 0, 0);        \
      acc01 = __builtin_amdgcn_mfma_f32_16x16x32_bf16(af0, bg1, acc01, 0, 0, 0);        \
      acc10 = __builtin_amdgcn_mfma_f32_16x16x32_bf16(af1, bg0, acc10, 0, 0, 0);        \
      acc11 = __builtin_amdgcn_mfma_f32_16x16x32_bf16(af1, bg1, acc11, 0, 0, 0);        \
    }                                                                         \
  } while (0)

__global__ __launch_bounds__(256) void k_gemm2(
    const ushort* __restrict__ xbf, const ushort* __restrict__ inpbf,
    const float* __restrict__ nrmx, const float* __restrict__ nrmi,
    float* __restrict__ eig, double* __restrict__ scal,
    unsigned long long* __restrict__ cnt)
{
  int id = blockIdx.x;
  int b = id & 7;
  int tm = id >> 3;                 // 0..71
  int mode = (tm >= 36) ? 1 : 0;
  int t = tm - mode * 36;           // 0..35 lower-triangle tile
  int bx = 0;
#pragma unroll
  for (int r = 1; r < 8; r++) if (t >= (r * (r + 1)) / 2) bx = r;
  int by = t - (bx * (bx + 1)) / 2;
  bool diag = (bx == by);
  int D = mode ? DII : DXX;
  const ushort* src = (mode ? inpbf : xbf) + (size_t)b * MBS * D;
  const float* nb = (mode ? nrmi : nrmx) + b * MBS;
  int row0 = bx * 64, col0 = by * 64;

  __shared__ ushort As[2][64 * LSTR];
  __shared__ ushort Bs[2][64 * LSTR];
  __shared__ double redd[256];
  __shared__ unsigned redi[256];

  int tid = threadIdx.x;
  int lane = tid & 63, w = tid >> 6;
  int wr = (w >> 1) * 32, wc = (w & 1) * 32;
  int l15 = lane & 15, l4 = lane >> 4;

  f32x4 acc00 = {0.f, 0.f, 0.f, 0.f}, acc01 = {0.f, 0.f, 0.f, 0.f};
  f32x4 acc10 = {0.f, 0.f, 0.f, 0.f}, acc11 = {0.f, 0.f, 0.f, 0.f};

  int rr = tid >> 3;            // 0..31
  int cc = (tid & 7) * 8;       // 0..56

  const ushort* srcA0 = src + (size_t)(row0 + rr) * D + cc;
  const ushort* srcA1 = src + (size_t)(row0 + 32 + rr) * D + cc;
  const ushort* srcB0 = src + (size_t)(col0 + rr) * D + cc;
  const ushort* srcB1 = src + (size_t)(col0 + 32 + rr) * D + cc;

  bf16x8 pa0, pa1, pb0, pb1;    // even steps -> buf 0
  bf16x8 qa0, qa1, qb0, qb1;    // odd steps  -> buf 1

  LOAD_SET(pa0, pa1, pb0, pb1, 0);
  LOAD_SET(qa0, qa1, qb0, qb1, 64);

  int nk = D >> 6;              // 128 (x) or 48 (inp), both even
  for (int k = 0; k < nk; k += 2) {
    // even step -> buf 0
    WRITE_LDS(0, pa0, pa1, pb0, pb1);
    __syncthreads();
    if (k + 2 < nk) LOAD_SET(pa0, pa1, pb0, pb1, (k + 2) << 6);
    MFMA_PHASE(0);
    // odd step -> buf 1
    WRITE_LDS(1, qa0, qa1, qb0, qb1);
    __syncthreads();
    if (k + 3 < nk) LOAD_SET(qa0, qa1, qb0, qb1, (k + 3) << 6);
    MFMA_PHASE(1);
  }

  // epilogue (C/D layout: col=lane&15, row=(lane>>4)*4+v); mirror off-diag
  float* dst = eig + slotOf(b, mode ? 0 : 1);
  double lsum = 0.0; unsigned lcnt = 0;
#define EPI(ACC, M, N)                                                        \
  do {                                                                        \
    int gr = row0 + wr + (M) * 16 + l4 * 4;                                   \
    int gc = col0 + wc + (N) * 16 + l15;                                      \
    float nj = nb[gc];                                                        \
    _Pragma("unroll")                                                         \
    for (int v = 0; v < 4; v++) {                                             \
      int gi = gr + v;                                                        \
      float d2 = nb[gi] + nj - 2.0f * ACC[v];                                 \
      d2 = fmaxf(d2, 0.0f);                                                   \
      if (gi == gc) d2 = 0.0f;                                                \
      float val;                                                              \
      if (mode == 0) {                                                        \
        val = d2;                                                             \
        if (d2 > 0.0f) { lsum += (double)sqrtf(d2); lcnt++; }                 \
      } else {                                                                \
        val = __expf(-d2 * (1.0f / 64.0f)) * (1.0f / 512.0f);                 \
        lsum += (double)val * val;                                            \
      }                                                                       \
      dst[(size_t)gi * MBS + gc] = val;                                       \
      if (!diag) dst[(size_t)gc * MBS + gi] = val;                            \
    }                                                                         \
  } while (0)
  EPI(acc00, 0, 0); EPI(acc01, 0, 1); EPI(acc10, 1, 0); EPI(acc11, 1, 1);
#undef EPI

  if (!diag) { lsum *= 2.0; lcnt *= 2; }
  __syncthreads();
  redd[tid] = lsum; redi[tid] = lcnt; __syncthreads();
  for (int o = 128; o > 0; o >>= 1) {
    if (tid < o) { redd[tid] += redd[tid + o]; redi[tid] += redi[tid + o]; }
    __syncthreads();
  }
  if (tid == 0) {
    if (mode == 0) {
      atomicAdd(&scal[I_SUMD + b], redd[0]);
      atomicAdd(&cnt[b], (unsigned long long)redi[0]);
    } else {
      atomicAdd(&scal[I_AX2 + b], redd[0]);
    }
  }
}

// ---------------- sigma-search sums: 10 sigmas per block, float4 loads ----------------
__global__ __launch_bounds__(256) void k_loss(const float* __restrict__ eig,
                                              double* __restrict__ scal,
                                              const unsigned long long* __restrict__ cnt) {
  int b = blockIdx.z, g = blockIdx.y;
  double c = (double)cnt[b]; if (c < 1.0) c = 1.0;
  float md = (float)(scal[I_SUMD + b] / c);
  const float4* d2p = (const float4*)(eig + slotOf(b, 1));
  const float4* ayp = (const float4*)(eig + slotOf(b, 2));
  float inv[10];
  double ln[10], ld[10];
#pragma unroll
  for (int i = 0; i < 10; i++) {
    float sg = md * (0.1f + 0.198f * (float)(g * 10 + i));
    inv[i] = 1.0f / (sg * sg);
    ln[i] = 0.0; ld[i] = 0.0;
  }
  int base = blockIdx.x * 4096 + threadIdx.x;   // float4 units; grid.x = 16
  for (int l = 0; l < 16; l++) {
    float4 d2v = d2p[base + l * 256];
    float4 kyv = ayp[base + l * 256];
#pragma unroll
    for (int u = 0; u < 4; u++) {
      float d2 = ((const float*)&d2v)[u];
      float ky = ((const float*)&kyv)[u] * 512.0f;
#pragma unroll
      for (int i = 0; i < 10; i++) {
        float kk = __expf(-d2 * inv[i]);
        ln[i] += (double)(kk * ky);
        ld[i] += (double)(kk * kk);
      }
    }
  }
#pragma unroll
  for (int i = 0; i < 10; i++) {
    double a = ln[i], d = ld[i];
    for (int o = 32; o > 0; o >>= 1) {
      a += __shfl_down(a, o, 64);
      d += __shfl_down(d, o, 64);
    }
    if ((threadIdx.x & 63) == 0) {
      atomicAdd(&scal[I_NUM + b * NSIG + g * 10 + i], a);
      atomicAdd(&scal[I_DEN + b * NSIG + g * 10 + i], d);
    }
  }
}

// ---------------- argmax + EMA sigma chain ----------------
__global__ void k_sigma(double* __restrict__ scal, const unsigned long long* __restrict__ cnt) {
  if (threadIdx.x == 0) {
    double sigma = 0.0;
    for (int b = 0; b < NBATCH; b++) {
      double c = (double)cnt[b]; if (c < 1.0) c = 1.0;
      double md = scal[I_SUMD + b] / c;
      double kyf = sqrt(scal[I_KYF + b]);
      double best = -1.0; int bi = 0;
      for (int s = 0; s < NSIG; s++) {
        double num = scal[I_NUM + b * NSIG + s];
        double den = sqrt(scal[I_DEN + b * NSIG + s]) * kyf;
        double loss = num / den;
        if (loss > best) { best = loss; bi = s; }
      }
      double st = md * (0.1 + 0.198 * (double)bi);
      sigma = (b == 0) ? st : 0.5 * sigma + 0.5 * st;
      scal[I_SIGMA + b] = sigma;
    }
  }
}

// ---------------- A build + Schur products + off2 fusion ----------------
__global__ __launch_bounds__(256) void k_aj(float* __restrict__ eig,
                                            double* __restrict__ scal) {
  int b = blockIdx.y;
  float sg = (float)scal[I_SIGMA + b];
  float inv = 1.0f / (sg * sg);
  float* A        = eig + slotOf(b, 1);
  const float* AX = eig + slotOf(b, 0);
  const float* AY = eig + slotOf(b, 2);
  float* J1       = eig + slotOf(b, 3);
  float* J2       = eig + slotOf(b, 4);
  double s1 = 0.0, s2 = 0.0, s3 = 0.0;
  size_t base = (size_t)blockIdx.x * 2048 + (size_t)threadIdx.x * 8;
#pragma unroll
  for (int h = 0; h < 2; h++) {
    size_t e = base + h * 4;
    float4 d2v = *(float4*)&A[e];
    float4 axv = *(const float4*)&AX[e];
    float4 ayv = *(const float4*)&AY[e];
    float4 av, j1v, j2v;
#pragma unroll
    for (int u = 0; u < 4; u++) {
      float a = __expf(-((const float*)&d2v)[u] * inv) * (1.0f / 512.0f);
      float j1 = ((const float*)&axv)[u] * a;
      float j2 = a * ((const float*)&ayv)[u];
      ((float*)&av)[u] = a; ((float*)&j1v)[u] = j1; ((float*)&j2v)[u] = j2;
      s1 += (double)a * a; s2 += (double)j1 * j1; s3 += (double)j2 * j2;
    }
    *(float4*)&A[e] = av;
    *(float4*)&J1[e] = j1v;
    *(float4*)&J2[e] = j2v;
  }
  __shared__ double r1[256], r2[256], r3[256];
  r1[threadIdx.x] = s1; r2[threadIdx.x] = s2; r3[threadIdx.x] = s3;
  __syncthreads();
  for (int o = 128; o > 0; o >>= 1) {
    if (threadIdx.x < o) {
      r1[threadIdx.x] += r1[threadIdx.x + o];
      r2[threadIdx.x] += r2[threadIdx.x + o];
      r3[threadIdx.x] += r3[threadIdx.x + o];
    }
    __syncthreads();
  }
  if (threadIdx.x == 0) {
    atomicAdd(&scal[I_A2 + b], r1[0]);
    atomicAdd(&scal[I_JX2 + b], r2[0]);
    atomicAdd(&scal[I_JY2 + b], r3[0]);
  }
}

// ---------------- entropies: closed-form fast path, Jacobi fallback ----------------
__global__ __launch_bounds__(512) void k_eigen(float* __restrict__ eig, double* __restrict__ scal) {
  int blk = blockIdx.x; int b = blk / 5, m = blk % 5;
  double off2, scale0;
  if (m == 0)      { off2 = scal[I_AX2 + b] - (1.0 / 512.0);              scale0 = 1.0; }
  else if (m == 1) { off2 = scal[I_A2 + b]  - (1.0 / 512.0);              scale0 = 1.0; }
  else if (m == 2) { off2 = (scal[I_KYF + b] - 512.0) * (1.0 / 262144.0); scale0 = 1.0; }
  else if (m == 3) { off2 = scal[I_JX2 + b] - 7.450580596923828125e-9;    scale0 = 512.0; }
  else             { off2 = scal[I_JY2 + b] - 7.450580596923828125e-9;    scale0 = 512.0; }

  if (off2 * scale0 * scale0 <= 1e-8) {   // entropy err ~739*off2: negligible
    if (threadIdx.x == 0) {
      double diagv = (m >= 3) ? (1.0 / 262144.0) : (1.0 / 512.0);
      double wv = diagv * scale0 + 1e-6;
      scal[I_ENT + b * 5 + m] = -512.0 * wv * log2(wv);
    }
    return;
  }

  // ---- Jacobi fallback (reads the materialized matrix) ----
  float* M = eig + slotOf(b, m);
  int t = threadIdx.x;
  __shared__ double red[512];
  __shared__ float csA[256], csB[256];
  __shared__ int anyrot;
  __shared__ double sh_scale, sh_off2;

  red[t] = (double)M[(size_t)t * 513]; __syncthreads();
  for (int o = 256; o > 0; o >>= 1) { if (t < o) red[t] += red[t + o]; __syncthreads(); }
  if (t == 0) { double trace = red[0]; sh_scale = (m >= 3) ? 1.0 / trace : 1.0; }
  __syncthreads();
  double scale = sh_scale;

  for (int sweep = 0; sweep < 30; sweep++) {
    double c2 = 0.0;
    for (int i = 0; i < 512; i++) {
      if (i != t) { float v = M[(size_t)i * 512 + t]; c2 += (double)v * v; }
    }
    red[t] = c2; __syncthreads();
    for (int o = 256; o > 0; o >>= 1) { if (t < o) red[t] += red[t + o]; __syncthreads(); }
    if (t == 0) sh_off2 = red[0];
    __syncthreads();
    if (sh_off2 * scale * scale <= 1e-8) break;

    for (int r = 0; r < 511; r++) {
      if (t == 0) anyrot = 0;
      __syncthreads();
      if (t < 256) {
        int p, q;
        if (t == 0) { p = 511; q = r; }
        else { p = (r + t) % 511; q = (r + 511 - t) % 511; }
        float app = M[(size_t)p * 512 + p];
        float aqq = M[(size_t)q * 512 + q];
        float apq = M[(size_t)p * 512 + q];
        float c = 1.0f, sr = 0.0f;
        if (fabsf(apq) > 1e-12f) {
          float th = (aqq - app) / (2.0f * apq);
          float tt = ((th >= 0.0f) ? 1.0f : -1.0f) / (fabsf(th) + sqrtf(1.0f + th * th));
          c = 1.0f / sqrtf(1.0f + tt * tt);
          sr = tt * c;
          anyrot = 1;
        }
        csA[t] = c; csB[t] = sr;
      }
      __syncthreads();
      if (anyrot) {
        int pair = t >> 1, half = t & 1;
        float c = csA[pair], sr = csB[pair];
        int p, q;
        if (pair == 0) { p = 511; q = r; }
        else { p = (r + pair) % 511; q = (r + 511 - pair) % 511; }
        if (sr != 0.0f) {
          size_t rp = (size_t)p * 512, rq = (size_t)q * 512;
          int j0 = half * 256;
          for (int j = j0; j < j0 + 256; j++) {
            float xx = M[rp + j], yy = M[rq + j];
            M[rp + j] = c * xx - sr * yy;
            M[rq + j] = sr * xx + c * yy;
          }
        }
        __syncthreads();
        if (sr != 0.0f) {
          int j0 = half * 256;
          for (int j = j0; j < j0 + 256; j++) {
            float xx = M[(size_t)j * 512 + p], yy = M[(size_t)j * 512 + q];
            M[(size_t)j * 512 + p] = c * xx - sr * yy;
            M[(size_t)j * 512 + q] = sr * xx + c * yy;
          }
        }
      }
      __syncthreads();
    }
  }

  double wv = (double)M[(size_t)t * 513] * scale + 1e-6;
  red[t] = -wv * log2(wv); __syncthreads();
  for (int o = 256; o > 0; o >>= 1) { if (t < o) red[t] += red[t + o]; __syncthreads(); }
  if (t == 0) scal[I_ENT + b * 5 + m] = red[0];
}

// ---------------- finalize MI means ----------------
__global__ void k_final(const double* __restrict__ scal, float* __restrict__ out) {
  if (threadIdx.x == 0) {
    double ixt = 0.0, ity = 0.0;
    for (int b = 0; b < NBATCH; b++) {
      const double* E = &scal[I_ENT + b * 5];
      ixt += E[0] + E[1] - E[3];
      ity += E[1] + E[2] - E[4];
    }
    out[NTOT]     = (float)(ixt / 8.0);
    out[NTOT + 1] = (float)(ity / 8.0);
  }
}

extern "C" void kernel_launch(void* const* d_in, const int* in_sizes, int n_in,
                              void* d_out, int out_size, void* d_ws, size_t ws_size,
                              hipStream_t stream) {
  const float* x   = (const float*)d_in[0];
  const float* inp = (const float*)d_in[1];
  const float* lab = (const float*)d_in[2];
  float* out = (float*)d_out;

  char* ws = (char*)d_ws;
  double* scal = (double*)ws;                                  // 944 doubles = 7552 B
  unsigned long long* cnt = (unsigned long long*)(ws + 7552);  // 64 B -> 7616
  float* nrmx = (float*)(ws + 7680);                           // 16 KB
  float* nrmi = (float*)(ws + 24064);                          // 16 KB -> 40448

  // Scratch: eig(40MB) + xbf(64MB) + inpbf(24MB) = 134217728 B exactly.
  const size_t EIG_OFF = 65536;
  bool big = ws_size >= EIG_OFF + 134217728ULL;
  char* base = big ? (ws + EIG_OFF) : (char*)d_out;
  float* eig = (float*)base;
  ushort* xbf = (ushort*)(base + 41943040);       // 40*NN*4
  ushort* inpbf = (ushort*)(base + 109051904);    // +4096*8192*2

  hipMemsetAsync(ws, 0, 7616, stream);

  if (big) k_prep_x<1><<<4096, 256, 0, stream>>>((const float4*)x, (float4*)d_out, xbf, nrmx);
  else     k_prep_x<0><<<4096, 256, 0, stream>>>((const float4*)x, nullptr, xbf, nrmx);
  k_prep_i<<<4096, 384, 0, stream>>>(inp, inpbf, nrmi);
  k_ky<<<dim3(256, NBATCH), 256, 0, stream>>>(lab, eig, scal);
  k_gemm2<<<576, 256, 0, stream>>>(xbf, inpbf, nrmx, nrmi, eig, scal, cnt);
  k_loss<<<dim3(16, 5, NBATCH), 256, 0, stream>>>(eig, scal, cnt);
  k_sigma<<<1, 64, 0, stream>>>(scal, cnt);
  k_aj<<<dim3(128, NBATCH), 256, 0, stream>>>(eig, scal);
  k_eigen<<<40, 512, 0, stream>>>(eig, scal);
  k_final<<<1, 64, 0, stream>>>(scal, out);
  if (!big) {
    k_copy<<<2048, 256, 0, stream>>>((const float4*)x, (float4*)d_out, NTOT / 4);
  }
}

// Round 8
// 315.733 us; speedup vs baseline: 12.6903x; 1.0812x over previous
//
#include <hip/hip_runtime.h>
#include <hip/hip_bf16.h>
#include <math.h>

// InformationPlane R8:
// - gemm2: raw s_barrier + lgkmcnt(0)-only drain (no vmcnt(0) at barriers) so
//   the depth-2 register prefetch actually stays in flight across K-steps.
//   Uniform B-loads (diag loads its panel twice) keep vmcnt counting static.
// - k_prep: prep_x + prep_i + k_ky fused (block-range dispatch), coalesced
//   float4 reads / ushort4 writes.
// - k_loss: last-block (done-counter) runs the sigma argmax/EMA chain.
// - k_eigen: last-block computes the final MI means.
// k_eigen closed-form fast path (off2 fused into producers), Jacobi fallback.

#define NBATCH 8
#define MBS    512
#define DXX    8192
#define DII    3072
#define NSIG   50
#define NN     262144                 // 512*512
#define NTOT   ((size_t)33554432)     // 4096*8192

// scal (double) indices
#define I_SUMD  0    // 8
#define I_KYF   8    // 8
#define I_SIGMA 24   // 8
#define I_ENT   32   // 40 (b*5+m)
#define I_NUM   96   // 8*50
#define I_DEN   512  // 8*50 -> 912
#define I_AX2   912  // 8  sum ax^2
#define I_A2    920  // 8  sum a^2
#define I_JX2   928  // 8  sum (ax*a)^2
#define I_JY2   936  // 8  sum (a*ay)^2 -> ends 944

typedef __attribute__((ext_vector_type(8))) short bf16x8;
typedef __attribute__((ext_vector_type(4))) float f32x4;

__device__ __forceinline__ size_t slotOf(int b, int m) {
  return ((size_t)(b * 5 + m)) * (size_t)NN;
}

__device__ __forceinline__ short f2b(float f) {
  __hip_bfloat16 h = __float2bfloat16(f);
  return *(short*)&h;
}

// ---------------- copy x -> out (small-ws path only) ----------------
__global__ void k_copy(const float4* __restrict__ src, float4* __restrict__ dst, size_t n4) {
  size_t i = (size_t)blockIdx.x * blockDim.x + threadIdx.x;
  size_t stride = (size_t)gridDim.x * blockDim.x;
  for (; i < n4; i += stride) dst[i] = src[i];
}

// ---------------- fused prep: x-rows | inp-rows | Ky ----------------
// blocks [0,4096): x row norm + bf16 (+optional copy)
// blocks [4096,6144): inp 2-row bf16 + norms
// blocks [6144,8192): Ky -> Ay slot + ||Ky||F^2
__global__ __launch_bounds__(256) void k_prep(
    const float4* __restrict__ x4, float4* __restrict__ xcopy, int docopy,
    const float* __restrict__ inp, const float* __restrict__ lab,
    ushort* __restrict__ xbf, ushort* __restrict__ inpbf,
    float* __restrict__ nrmx, float* __restrict__ nrmi,
    float* __restrict__ eig, double* __restrict__ scal)
{
  __shared__ double red[256];
  int bid = blockIdx.x, t = threadIdx.x;

  if (bid < 4096) {                       // ---- x rows ----
    int row = bid;
    const float4* p4 = x4 + (size_t)row * 2048;
    ushort4* o4 = (ushort4*)(xbf + (size_t)row * 8192);
    float4* q4 = xcopy + (size_t)row * 2048;
    double s = 0.0;
#pragma unroll
    for (int l = 0; l < 8; l++) {
      int f = l * 256 + t;
      float4 a = p4[f];
      if (docopy) q4[f] = a;
      ushort4 v;
      v.x = (ushort)f2b(a.x); v.y = (ushort)f2b(a.y);
      v.z = (ushort)f2b(a.z); v.w = (ushort)f2b(a.w);
      o4[f] = v;
      s += (double)a.x * a.x + (double)a.y * a.y + (double)a.z * a.z + (double)a.w * a.w;
    }
    red[t] = s; __syncthreads();
    for (int o = 128; o > 0; o >>= 1) {
      if (t < o) red[t] += red[t + o];
      __syncthreads();
    }
    if (t == 0) nrmx[row] = (float)red[0];
    return;
  }

  if (bid < 6144) {                       // ---- inp: 2 rows per block ----
    int p = bid - 4096;                   // row pair
    const float4* src4 = (const float4*)inp + (size_t)p * 768;
    ushort4* dst4 = (ushort4*)inpbf + (size_t)p * 768;
    double s0 = 0.0, s1 = 0.0;
#pragma unroll
    for (int j = 0; j < 3; j++) {
      int f = j * 256 + t;
      float4 a = src4[f];
      ushort4 v;
      v.x = (ushort)f2b(a.x); v.y = (ushort)f2b(a.y);
      v.z = (ushort)f2b(a.z); v.w = (ushort)f2b(a.w);
      dst4[f] = v;
      double ss = (double)a.x * a.x + (double)a.y * a.y + (double)a.z * a.z + (double)a.w * a.w;
      if (f < 384) s0 += ss; else s1 += ss;
    }
    red[t] = s0; __syncthreads();
    for (int o = 128; o > 0; o >>= 1) { if (t < o) red[t] += red[t + o]; __syncthreads(); }
    if (t == 0) nrmi[2 * p] = (float)red[0];
    __syncthreads();
    red[t] = s1; __syncthreads();
    for (int o = 128; o > 0; o >>= 1) { if (t < o) red[t] += red[t + o]; __syncthreads(); }
    if (t == 0) nrmi[2 * p + 1] = (float)red[0];
    return;
  }

  // ---- Ky ----
  int idx = bid - 6144;                   // 0..2047
  int b = idx >> 8, xb = idx & 255;
  int e0 = xb * 1024 + t * 4;
  int i = e0 >> 9;
  const float* L = lab + (size_t)b * MBS * 10;
  float4 out;
  double s = 0.0;
#pragma unroll
  for (int u = 0; u < 4; u++) {
    int j = (e0 & 511) + u;
    float d2 = 0.0f;
#pragma unroll
    for (int d = 0; d < 10; d++) { float dd = L[i * 10 + d] - L[j * 10 + d]; d2 += dd * dd; }
    float ky = __expf(-d2 * 100.0f);
    ((float*)&out)[u] = ky * (1.0f / 512.0f);
    s += (double)ky * ky;
  }
  *(float4*)&eig[slotOf(b, 2) + e0] = out;
  red[t] = s; __syncthreads();
  for (int o = 128; o > 0; o >>= 1) { if (t < o) red[t] += red[t + o]; __syncthreads(); }
  if (t == 0) atomicAdd(&scal[I_KYF + b], red[0]);
}

// ---------------- symmetric bf16-MFMA pdist2 GEMM, 64x64 tiles ----------------
// 576 blocks: id%8 = batch; tm<36 -> mode0 (x), else mode1 (inp).
// Static 2-deep pipeline; raw s_barrier keeps prefetch loads in flight.
#define LSTR 72
#define LGKM0_BAR                                                             \
  do {                                                                        \
    asm volatile("s_waitcnt lgkmcnt(0)" ::: "memory");                        \
    __builtin_amdgcn_s_barrier();                                             \
    __builtin_amdgcn_sched_barrier(0);                                        \
  } while (0)

#define LOAD_SET(A0, A1, B0, B1, K0)                                          \
  do {                                                                        \
    A0 = *(const bf16x8*)&srcA0[K0];                                          \
    A1 = *(const bf16x8*)&srcA1[K0];                                          \
    B0 = *(const bf16x8*)&srcB0[K0];                                          \
    B1 = *(const bf16x8*)&srcB1[K0];                                          \
  } while (0)

#define WRITE_LDS(BUF, A0, A1, B0, B1)                                        \
  do {                                                                        \
    *(bf16x8*)&As[BUF][rr * LSTR + cc] = A0;                                  \
    *(bf16x8*)&As[BUF][(32 + rr) * LSTR + cc] = A1;                           \
    *(bf16x8*)&Bs[BUF][rr * LSTR + cc] = B0;                                  \
    *(bf16x8*)&Bs[BUF][(32 + rr) * LSTR + cc] = B1;                           \
  } while (0)

#define MFMA_PHASE(BUF)                                                       \
  do {                                                                        \
    _Pragma("unroll")                                                         \
    for (int ks = 0; ks < 2; ks++) {                                          \
      bf16x8 af0 = *(const bf16x8*)&As[BUF][(wr + l15) * LSTR + ks * 32 + l4 * 8];          \
      bf16x8 af1 = *(const bf16x8*)&As[BUF][(wr + 16 + l15) * LSTR + ks * 32 + l4 * 8];     \
      bf16x8 bg0 = *(const bf16x8*)&Bs[BUF][(wc + l15) * LSTR + ks * 32 + l4 * 8];          \
      bf16x8 bg1 = *(const bf16x8*)&Bs[BUF][(wc + 16 + l15) * LSTR + ks * 32 + l4 * 8];     \
      acc00 = __builtin_amdgcn_mfma_f32_16x16x32_bf16(af0, bg0, acc00, 0, 0, 0);            \
      acc01 = __builtin_amdgcn_mfma_f32_16x16x32_bf16(af0, bg1, acc01, 0, 0, 0);            \
      acc10 = __builtin_amdgcn_mfma_f32_16x16x32_bf16(af1, bg0, acc10, 0, 0, 0);            \
      acc11 = __builtin_amdgcn_mfma_f32_16x16x32_bf16(af1, bg1, acc11, 0, 0, 0);            \
    }                                                                         \
  } while (0)

__global__ __launch_bounds__(256) void k_gemm2(
    const ushort* __restrict__ xbf, const ushort* __restrict__ inpbf,
    const float* __restrict__ nrmx, const float* __restrict__ nrmi,
    float* __restrict__ eig, double* __restrict__ scal,
    unsigned long long* __restrict__ cnt)
{
  int id = blockIdx.x;
  int b = id & 7;
  int tm = id >> 3;                 // 0..71
  int mode = (tm >= 36) ? 1 : 0;
  int t = tm - mode * 36;           // 0..35 lower-triangle tile
  int bx = 0;
#pragma unroll
  for (int r = 1; r < 8; r++) if (t >= (r * (r + 1)) / 2) bx = r;
  int by = t - (bx * (bx + 1)) / 2;
  bool diag = (bx == by);
  int D = mode ? DII : DXX;
  const ushort* src = (mode ? inpbf : xbf) + (size_t)b * MBS * D;
  const float* nb = (mode ? nrmi : nrmx) + b * MBS;
  int row0 = bx * 64, col0 = by * 64;

  __shared__ ushort As[2][64 * LSTR];
  __shared__ ushort Bs[2][64 * LSTR];
  __shared__ double redd[256];
  __shared__ unsigned redi[256];

  int tid = threadIdx.x;
  int lane = tid & 63, w = tid >> 6;
  int wr = (w >> 1) * 32, wc = (w & 1) * 32;
  int l15 = lane & 15, l4 = lane >> 4;

  f32x4 acc00 = {0.f, 0.f, 0.f, 0.f}, acc01 = {0.f, 0.f, 0.f, 0.f};
  f32x4 acc10 = {0.f, 0.f, 0.f, 0.f}, acc11 = {0.f, 0.f, 0.f, 0.f};

  int rr = tid >> 3;            // 0..31
  int cc = (tid & 7) * 8;       // 0..56

  const ushort* srcA0 = src + (size_t)(row0 + rr) * D + cc;
  const ushort* srcA1 = src + (size_t)(row0 + 32 + rr) * D + cc;
  const ushort* srcB0 = src + (size_t)(col0 + rr) * D + cc;
  const ushort* srcB1 = src + (size_t)(col0 + 32 + rr) * D + cc;

  bf16x8 pa0, pa1, pb0, pb1;    // even steps -> buf 0
  bf16x8 qa0, qa1, qb0, qb1;    // odd steps  -> buf 1

  LOAD_SET(pa0, pa1, pb0, pb1, 0);
  LOAD_SET(qa0, qa1, qb0, qb1, 64);

  int nk = D >> 6;              // 128 (x) or 48 (inp), both even
  for (int k = 0; k < nk; k += 2) {
    // even step -> buf 0
    WRITE_LDS(0, pa0, pa1, pb0, pb1);
    if (k + 2 < nk) LOAD_SET(pa0, pa1, pb0, pb1, (k + 2) << 6);
    LGKM0_BAR;                  // LDS drain only; prefetch stays in flight
    MFMA_PHASE(0);
    // odd step -> buf 1
    WRITE_LDS(1, qa0, qa1, qb0, qb1);
    if (k + 3 < nk) LOAD_SET(qa0, qa1, qb0, qb1, (k + 3) << 6);
    LGKM0_BAR;
    MFMA_PHASE(1);
  }

  // epilogue (C/D layout: col=lane&15, row=(lane>>4)*4+v); mirror off-diag
  float* dst = eig + slotOf(b, mode ? 0 : 1);
  double lsum = 0.0; unsigned lcnt = 0;
#define EPI(ACC, M, N)                                                        \
  do {                                                                        \
    int gr = row0 + wr + (M) * 16 + l4 * 4;                                   \
    int gc = col0 + wc + (N) * 16 + l15;                                      \
    float nj = nb[gc];                                                        \
    _Pragma("unroll")                                                         \
    for (int v = 0; v < 4; v++) {                                             \
      int gi = gr + v;                                                        \
      float d2 = nb[gi] + nj - 2.0f * ACC[v];                                 \
      d2 = fmaxf(d2, 0.0f);                                                   \
      if (gi == gc) d2 = 0.0f;                                                \
      float val;                                                              \
      if (mode == 0) {                                                        \
        val = d2;                                                             \
        if (d2 > 0.0f) { lsum += (double)sqrtf(d2); lcnt++; }                 \
      } else {                                                                \
        val = __expf(-d2 * (1.0f / 64.0f)) * (1.0f / 512.0f);                 \
        lsum += (double)val * val;                                            \
      }                                                                       \
      dst[(size_t)gi * MBS + gc] = val;                                       \
      if (!diag) dst[(size_t)gc * MBS + gi] = val;                            \
    }                                                                         \
  } while (0)
  EPI(acc00, 0, 0); EPI(acc01, 0, 1); EPI(acc10, 1, 0); EPI(acc11, 1, 1);
#undef EPI

  if (!diag) { lsum *= 2.0; lcnt *= 2; }
  __syncthreads();
  redd[tid] = lsum; redi[tid] = lcnt; __syncthreads();
  for (int o = 128; o > 0; o >>= 1) {
    if (tid < o) { redd[tid] += redd[tid + o]; redi[tid] += redi[tid + o]; }
    __syncthreads();
  }
  if (tid == 0) {
    if (mode == 0) {
      atomicAdd(&scal[I_SUMD + b], redd[0]);
      atomicAdd(&cnt[b], (unsigned long long)redi[0]);
    } else {
      atomicAdd(&scal[I_AX2 + b], redd[0]);
    }
  }
}

// ---------------- sigma-search sums + fused argmax/EMA (last block) ----------------
__global__ __launch_bounds__(256) void k_loss(const float* __restrict__ eig,
                                              double* __restrict__ scal,
                                              const unsigned long long* __restrict__ cnt,
                                              unsigned* __restrict__ done) {
  int b = blockIdx.z, g = blockIdx.y;
  double c = (double)cnt[b]; if (c < 1.0) c = 1.0;
  float md = (float)(scal[I_SUMD + b] / c);
  const float4* d2p = (const float4*)(eig + slotOf(b, 1));
  const float4* ayp = (const float4*)(eig + slotOf(b, 2));
  float inv[10];
  double ln[10], ld[10];
#pragma unroll
  for (int i = 0; i < 10; i++) {
    float sg = md * (0.1f + 0.198f * (float)(g * 10 + i));
    inv[i] = 1.0f / (sg * sg);
    ln[i] = 0.0; ld[i] = 0.0;
  }
  int base = blockIdx.x * 4096 + threadIdx.x;   // float4 units; grid.x = 16
  for (int l = 0; l < 16; l++) {
    float4 d2v = d2p[base + l * 256];
    float4 kyv = ayp[base + l * 256];
#pragma unroll
    for (int u = 0; u < 4; u++) {
      float d2 = ((const float*)&d2v)[u];
      float ky = ((const float*)&kyv)[u] * 512.0f;
#pragma unroll
      for (int i = 0; i < 10; i++) {
        float kk = __expf(-d2 * inv[i]);
        ln[i] += (double)(kk * ky);
        ld[i] += (double)(kk * kk);
      }
    }
  }
#pragma unroll
  for (int i = 0; i < 10; i++) {
    double a = ln[i], d = ld[i];
    for (int o = 32; o > 0; o >>= 1) {
      a += __shfl_down(a, o, 64);
      d += __shfl_down(d, o, 64);
    }
    if ((threadIdx.x & 63) == 0) {
      atomicAdd(&scal[I_NUM + b * NSIG + g * 10 + i], a);
      atomicAdd(&scal[I_DEN + b * NSIG + g * 10 + i], d);
    }
  }
  __syncthreads();
  if (threadIdx.x == 0) {
    __threadfence();
    unsigned r = atomicAdd(done, 1u);
    if (r == 16 * 5 * NBATCH - 1) {        // last block: sigma chain
      __threadfence();
      double sigma = 0.0;
      for (int bb = 0; bb < NBATCH; bb++) {
        double cc2 = (double)cnt[bb]; if (cc2 < 1.0) cc2 = 1.0;
        double mdd = scal[I_SUMD + bb] / cc2;
        double kyf = sqrt(scal[I_KYF + bb]);
        double best = -1.0; int bi = 0;
        for (int s = 0; s < NSIG; s++) {
          double num = scal[I_NUM + bb * NSIG + s];
          double den = sqrt(scal[I_DEN + bb * NSIG + s]) * kyf;
          double loss = num / den;
          if (loss > best) { best = loss; bi = s; }
        }
        double st = mdd * (0.1 + 0.198 * (double)bi);
        sigma = (bb == 0) ? st : 0.5 * sigma + 0.5 * st;
        scal[I_SIGMA + bb] = sigma;
      }
    }
  }
}

// ---------------- A build + Schur products + off2 fusion ----------------
__global__ __launch_bounds__(256) void k_aj(float* __restrict__ eig,
                                            double* __restrict__ scal) {
  int b = blockIdx.y;
  float sg = (float)scal[I_SIGMA + b];
  float inv = 1.0f / (sg * sg);
  float* A        = eig + slotOf(b, 1);
  const float* AX = eig + slotOf(b, 0);
  const float* AY = eig + slotOf(b, 2);
  float* J1       = eig + slotOf(b, 3);
  float* J2       = eig + slotOf(b, 4);
  double s1 = 0.0, s2 = 0.0, s3 = 0.0;
  size_t base = (size_t)blockIdx.x * 2048 + (size_t)threadIdx.x * 8;
#pragma unroll
  for (int h = 0; h < 2; h++) {
    size_t e = base + h * 4;
    float4 d2v = *(float4*)&A[e];
    float4 axv = *(const float4*)&AX[e];
    float4 ayv = *(const float4*)&AY[e];
    float4 av, j1v, j2v;
#pragma unroll
    for (int u = 0; u < 4; u++) {
      float a = __expf(-((const float*)&d2v)[u] * inv) * (1.0f / 512.0f);
      float j1 = ((const float*)&axv)[u] * a;
      float j2 = a * ((const float*)&ayv)[u];
      ((float*)&av)[u] = a; ((float*)&j1v)[u] = j1; ((float*)&j2v)[u] = j2;
      s1 += (double)a * a; s2 += (double)j1 * j1; s3 += (double)j2 * j2;
    }
    *(float4*)&A[e] = av;
    *(float4*)&J1[e] = j1v;
    *(float4*)&J2[e] = j2v;
  }
  __shared__ double r1[256], r2[256], r3[256];
  r1[threadIdx.x] = s1; r2[threadIdx.x] = s2; r3[threadIdx.x] = s3;
  __syncthreads();
  for (int o = 128; o > 0; o >>= 1) {
    if (threadIdx.x < o) {
      r1[threadIdx.x] += r1[threadIdx.x + o];
      r2[threadIdx.x] += r2[threadIdx.x + o];
      r3[threadIdx.x] += r3[threadIdx.x + o];
    }
    __syncthreads();
  }
  if (threadIdx.x == 0) {
    atomicAdd(&scal[I_A2 + b], r1[0]);
    atomicAdd(&scal[I_JX2 + b], r2[0]);
    atomicAdd(&scal[I_JY2 + b], r3[0]);
  }
}

// ---------------- entropies (closed-form / Jacobi) + fused final ----------------
__global__ __launch_bounds__(512) void k_eigen(float* __restrict__ eig,
                                               double* __restrict__ scal,
                                               unsigned* __restrict__ done,
                                               float* __restrict__ out) {
  int blk = blockIdx.x; int b = blk / 5, m = blk % 5;
  int t = threadIdx.x;
  double off2, scale0;
  if (m == 0)      { off2 = scal[I_AX2 + b] - (1.0 / 512.0);              scale0 = 1.0; }
  else if (m == 1) { off2 = scal[I_A2 + b]  - (1.0 / 512.0);              scale0 = 1.0; }
  else if (m == 2) { off2 = (scal[I_KYF + b] - 512.0) * (1.0 / 262144.0); scale0 = 1.0; }
  else if (m == 3) { off2 = scal[I_JX2 + b] - 7.450580596923828125e-9;    scale0 = 512.0; }
  else             { off2 = scal[I_JY2 + b] - 7.450580596923828125e-9;    scale0 = 512.0; }

  if (off2 * scale0 * scale0 <= 1e-8) {   // entropy err ~739*off2: negligible
    if (t == 0) {
      double diagv = (m >= 3) ? (1.0 / 262144.0) : (1.0 / 512.0);
      double wv = diagv * scale0 + 1e-6;
      scal[I_ENT + b * 5 + m] = -512.0 * wv * log2(wv);
    }
  } else {
    // ---- Jacobi fallback (reads the materialized matrix) ----
    float* M = eig + slotOf(b, m);
    __shared__ double red[512];
    __shared__ float csA[256], csB[256];
    __shared__ int anyrot;
    __shared__ double sh_scale, sh_off2;

    red[t] = (double)M[(size_t)t * 513]; __syncthreads();
    for (int o = 256; o > 0; o >>= 1) { if (t < o) red[t] += red[t + o]; __syncthreads(); }
    if (t == 0) { double trace = red[0]; sh_scale = (m >= 3) ? 1.0 / trace : 1.0; }
    __syncthreads();
    double scale = sh_scale;

    for (int sweep = 0; sweep < 30; sweep++) {
      double c2 = 0.0;
      for (int i = 0; i < 512; i++) {
        if (i != t) { float v = M[(size_t)i * 512 + t]; c2 += (double)v * v; }
      }
      red[t] = c2; __syncthreads();
      for (int o = 256; o > 0; o >>= 1) { if (t < o) red[t] += red[t + o]; __syncthreads(); }
      if (t == 0) sh_off2 = red[0];
      __syncthreads();
      if (sh_off2 * scale * scale <= 1e-8) break;

      for (int r = 0; r < 511; r++) {
        if (t == 0) anyrot = 0;
        __syncthreads();
        if (t < 256) {
          int p, q;
          if (t == 0) { p = 511; q = r; }
          else { p = (r + t) % 511; q = (r + 511 - t) % 511; }
          float app = M[(size_t)p * 512 + p];
          float aqq = M[(size_t)q * 512 + q];
          float apq = M[(size_t)p * 512 + q];
          float c = 1.0f, sr = 0.0f;
          if (fabsf(apq) > 1e-12f) {
            float th = (aqq - app) / (2.0f * apq);
            float tt = ((th >= 0.0f) ? 1.0f : -1.0f) / (fabsf(th) + sqrtf(1.0f + th * th));
            c = 1.0f / sqrtf(1.0f + tt * tt);
            sr = tt * c;
            anyrot = 1;
          }
          csA[t] = c; csB[t] = sr;
        }
        __syncthreads();
        if (anyrot) {
          int pair = t >> 1, half = t & 1;
          float c = csA[pair], sr = csB[pair];
          int p, q;
          if (pair == 0) { p = 511; q = r; }
          else { p = (r + pair) % 511; q = (r + 511 - pair) % 511; }
          if (sr != 0.0f) {
            size_t rp = (size_t)p * 512, rq = (size_t)q * 512;
            int j0 = half * 256;
            for (int j = j0; j < j0 + 256; j++) {
              float xx = M[rp + j], yy = M[rq + j];
              M[rp + j] = c * xx - sr * yy;
              M[rq + j] = sr * xx + c * yy;
            }
          }
          __syncthreads();
          if (sr != 0.0f) {
            int j0 = half * 256;
            for (int j = j0; j < j0 + 256; j++) {
              float xx = M[(size_t)j * 512 + p], yy = M[(size_t)j * 512 + q];
              M[(size_t)j * 512 + p] = c * xx - sr * yy;
              M[(size_t)j * 512 + q] = sr * xx + c * yy;
            }
          }
        }
        __syncthreads();
      }
    }

    double wv = (double)M[(size_t)t * 513] * scale + 1e-6;
    red[t] = -wv * log2(wv); __syncthreads();
    for (int o = 256; o > 0; o >>= 1) { if (t < o) red[t] += red[t + o]; __syncthreads(); }
    if (t == 0) scal[I_ENT + b * 5 + m] = red[0];
  }

  __syncthreads();
  if (t == 0) {
    __threadfence();
    unsigned r = atomicAdd(done, 1u);
    if (r == 39) {                        // last block: MI means
      __threadfence();
      double ixt = 0.0, ity = 0.0;
      for (int bb = 0; bb < NBATCH; bb++) {
        const double* E = &scal[I_ENT + bb * 5];
        ixt += E[0] + E[1] - E[3];
        ity += E[1] + E[2] - E[4];
      }
      out[NTOT]     = (float)(ixt / 8.0);
      out[NTOT + 1] = (float)(ity / 8.0);
    }
  }
}

extern "C" void kernel_launch(void* const* d_in, const int* in_sizes, int n_in,
                              void* d_out, int out_size, void* d_ws, size_t ws_size,
                              hipStream_t stream) {
  const float* x   = (const float*)d_in[0];
  const float* inp = (const float*)d_in[1];
  const float* lab = (const float*)d_in[2];
  float* out = (float*)d_out;

  char* ws = (char*)d_ws;
  double* scal = (double*)ws;                                  // 944 doubles = 7552 B
  unsigned long long* cnt = (unsigned long long*)(ws + 7552);  // 64 B -> 7616
  unsigned* done_loss = (unsigned*)(ws + 7616);                // 4 B
  unsigned* done_eig  = (unsigned*)(ws + 7620);                // 4 B -> 7624
  float* nrmx = (float*)(ws + 7680);                           // 16 KB
  float* nrmi = (float*)(ws + 24064);                          // 16 KB -> 40448

  // Scratch: eig(40MB) + xbf(64MB) + inpbf(24MB) = 134217728 B exactly.
  const size_t EIG_OFF = 65536;
  bool big = ws_size >= EIG_OFF + 134217728ULL;
  char* base = big ? (ws + EIG_OFF) : (char*)d_out;
  float* eig = (float*)base;
  ushort* xbf = (ushort*)(base + 41943040);       // 40*NN*4
  ushort* inpbf = (ushort*)(base + 109051904);    // +4096*8192*2

  hipMemsetAsync(ws, 0, 7624, stream);

  k_prep<<<8192, 256, 0, stream>>>((const float4*)x, (float4*)d_out, big ? 1 : 0,
                                   inp, lab, xbf, inpbf, nrmx, nrmi, eig, scal);
  k_gemm2<<<576, 256, 0, stream>>>(xbf, inpbf, nrmx, nrmi, eig, scal, cnt);
  k_loss<<<dim3(16, 5, NBATCH), 256, 0, stream>>>(eig, scal, cnt, done_loss);
  k_aj<<<dim3(128, NBATCH), 256, 0, stream>>>(eig, scal);
  k_eigen<<<40, 512, 0, stream>>>(eig, scal, done_eig, out);
  if (!big) {
    k_copy<<<2048, 256, 0, stream>>>((const float4*)x, (float4*)d_out, NTOT / 4);
  }
}

// Round 9
// 290.417 us; speedup vs baseline: 13.7965x; 1.0872x over previous
//
#include <hip/hip_runtime.h>
#include <hip/hip_bf16.h>
#include <math.h>

// InformationPlane R9: R8 + k_loss rebuilt. R8's k_loss spent 128us in fp64
// accumulation (20 f64 cvt/add per element, fraction-rate on CDNA4) at 22%
// VALUBusy. R9: 25 sigmas/block (grid 32x2x8), fp32 accumulators (static
// indices), per-wave shfl reduce, one fp64 atomic per wave per sigma (ky=512*ay
// scale folded there). Argmax margins (loss(0)~1.0 vs loss(2)=0.94, and
// s=0/s=1 downstream-identical) make fp32 safe by construction.

#define NBATCH 8
#define MBS    512
#define DXX    8192
#define DII    3072
#define NSIG   50
#define NN     262144                 // 512*512
#define NTOT   ((size_t)33554432)     // 4096*8192

// scal (double) indices
#define I_SUMD  0    // 8
#define I_KYF   8    // 8
#define I_SIGMA 24   // 8
#define I_ENT   32   // 40 (b*5+m)
#define I_NUM   96   // 8*50
#define I_DEN   512  // 8*50 -> 912
#define I_AX2   912  // 8  sum ax^2
#define I_A2    920  // 8  sum a^2
#define I_JX2   928  // 8  sum (ax*a)^2
#define I_JY2   936  // 8  sum (a*ay)^2 -> ends 944

typedef __attribute__((ext_vector_type(8))) short bf16x8;
typedef __attribute__((ext_vector_type(4))) float f32x4;

__device__ __forceinline__ size_t slotOf(int b, int m) {
  return ((size_t)(b * 5 + m)) * (size_t)NN;
}

__device__ __forceinline__ short f2b(float f) {
  __hip_bfloat16 h = __float2bfloat16(f);
  return *(short*)&h;
}

// ---------------- copy x -> out (small-ws path only) ----------------
__global__ void k_copy(const float4* __restrict__ src, float4* __restrict__ dst, size_t n4) {
  size_t i = (size_t)blockIdx.x * blockDim.x + threadIdx.x;
  size_t stride = (size_t)gridDim.x * blockDim.x;
  for (; i < n4; i += stride) dst[i] = src[i];
}

// ---------------- fused prep: x-rows | inp-rows | Ky ----------------
__global__ __launch_bounds__(256) void k_prep(
    const float4* __restrict__ x4, float4* __restrict__ xcopy, int docopy,
    const float* __restrict__ inp, const float* __restrict__ lab,
    ushort* __restrict__ xbf, ushort* __restrict__ inpbf,
    float* __restrict__ nrmx, float* __restrict__ nrmi,
    float* __restrict__ eig, double* __restrict__ scal)
{
  __shared__ double red[256];
  int bid = blockIdx.x, t = threadIdx.x;

  if (bid < 4096) {                       // ---- x rows ----
    int row = bid;
    const float4* p4 = x4 + (size_t)row * 2048;
    ushort4* o4 = (ushort4*)(xbf + (size_t)row * 8192);
    float4* q4 = xcopy + (size_t)row * 2048;
    double s = 0.0;
#pragma unroll
    for (int l = 0; l < 8; l++) {
      int f = l * 256 + t;
      float4 a = p4[f];
      if (docopy) q4[f] = a;
      ushort4 v;
      v.x = (ushort)f2b(a.x); v.y = (ushort)f2b(a.y);
      v.z = (ushort)f2b(a.z); v.w = (ushort)f2b(a.w);
      o4[f] = v;
      s += (double)a.x * a.x + (double)a.y * a.y + (double)a.z * a.z + (double)a.w * a.w;
    }
    red[t] = s; __syncthreads();
    for (int o = 128; o > 0; o >>= 1) {
      if (t < o) red[t] += red[t + o];
      __syncthreads();
    }
    if (t == 0) nrmx[row] = (float)red[0];
    return;
  }

  if (bid < 6144) {                       // ---- inp: 2 rows per block ----
    int p = bid - 4096;                   // row pair
    const float4* src4 = (const float4*)inp + (size_t)p * 768;
    ushort4* dst4 = (ushort4*)inpbf + (size_t)p * 768;
    double s0 = 0.0, s1 = 0.0;
#pragma unroll
    for (int j = 0; j < 3; j++) {
      int f = j * 256 + t;
      float4 a = src4[f];
      ushort4 v;
      v.x = (ushort)f2b(a.x); v.y = (ushort)f2b(a.y);
      v.z = (ushort)f2b(a.z); v.w = (ushort)f2b(a.w);
      dst4[f] = v;
      double ss = (double)a.x * a.x + (double)a.y * a.y + (double)a.z * a.z + (double)a.w * a.w;
      if (f < 384) s0 += ss; else s1 += ss;
    }
    red[t] = s0; __syncthreads();
    for (int o = 128; o > 0; o >>= 1) { if (t < o) red[t] += red[t + o]; __syncthreads(); }
    if (t == 0) nrmi[2 * p] = (float)red[0];
    __syncthreads();
    red[t] = s1; __syncthreads();
    for (int o = 128; o > 0; o >>= 1) { if (t < o) red[t] += red[t + o]; __syncthreads(); }
    if (t == 0) nrmi[2 * p + 1] = (float)red[0];
    return;
  }

  // ---- Ky ----
  int idx = bid - 6144;                   // 0..2047
  int b = idx >> 8, xb = idx & 255;
  int e0 = xb * 1024 + t * 4;
  int i = e0 >> 9;
  const float* L = lab + (size_t)b * MBS * 10;
  float4 out;
  double s = 0.0;
#pragma unroll
  for (int u = 0; u < 4; u++) {
    int j = (e0 & 511) + u;
    float d2 = 0.0f;
#pragma unroll
    for (int d = 0; d < 10; d++) { float dd = L[i * 10 + d] - L[j * 10 + d]; d2 += dd * dd; }
    float ky = __expf(-d2 * 100.0f);
    ((float*)&out)[u] = ky * (1.0f / 512.0f);
    s += (double)ky * ky;
  }
  *(float4*)&eig[slotOf(b, 2) + e0] = out;
  red[t] = s; __syncthreads();
  for (int o = 128; o > 0; o >>= 1) { if (t < o) red[t] += red[t + o]; __syncthreads(); }
  if (t == 0) atomicAdd(&scal[I_KYF + b], red[0]);
}

// ---------------- symmetric bf16-MFMA pdist2 GEMM, 64x64 tiles ----------------
#define LSTR 72
#define LGKM0_BAR                                                             \
  do {                                                                        \
    asm volatile("s_waitcnt lgkmcnt(0)" ::: "memory");                        \
    __builtin_amdgcn_s_barrier();                                             \
    __builtin_amdgcn_sched_barrier(0);                                        \
  } while (0)

#define LOAD_SET(A0, A1, B0, B1, K0)                                          \
  do {                                                                        \
    A0 = *(const bf16x8*)&srcA0[K0];                                          \
    A1 = *(const bf16x8*)&srcA1[K0];                                          \
    B0 = *(const bf16x8*)&srcB0[K0];                                          \
    B1 = *(const bf16x8*)&srcB1[K0];                                          \
  } while (0)

#define WRITE_LDS(BUF, A0, A1, B0, B1)                                        \
  do {                                                                        \
    *(bf16x8*)&As[BUF][rr * LSTR + cc] = A0;                                  \
    *(bf16x8*)&As[BUF][(32 + rr) * LSTR + cc] = A1;                           \
    *(bf16x8*)&Bs[BUF][rr * LSTR + cc] = B0;                                  \
    *(bf16x8*)&Bs[BUF][(32 + rr) * LSTR + cc] = B1;                           \
  } while (0)

#define MFMA_PHASE(BUF)                                                       \
  do {                                                                        \
    _Pragma("unroll")                                                         \
    for (int ks = 0; ks < 2; ks++) {                                          \
      bf16x8 af0 = *(const bf16x8*)&As[BUF][(wr + l15) * LSTR + ks * 32 + l4 * 8];          \
      bf16x8 af1 = *(const bf16x8*)&As[BUF][(wr + 16 + l15) * LSTR + ks * 32 + l4 * 8];     \
      bf16x8 bg0 = *(const bf16x8*)&Bs[BUF][(wc + l15) * LSTR + ks * 32 + l4 * 8];          \
      bf16x8 bg1 = *(const bf16x8*)&Bs[BUF][(wc + 16 + l15) * LSTR + ks * 32 + l4 * 8];     \
      acc00 = __builtin_amdgcn_mfma_f32_16x16x32_bf16(af0, bg0, acc00, 0, 0, 0);            \
      acc01 = __builtin_amdgcn_mfma_f32_16x16x32_bf16(af0, bg1, acc01, 0, 0, 0);            \
      acc10 = __builtin_amdgcn_mfma_f32_16x16x32_bf16(af1, bg0, acc10, 0, 0, 0);            \
      acc11 = __builtin_amdgcn_mfma_f32_16x16x32_bf16(af1, bg1, acc11, 0, 0, 0);            \
    }                                                                         \
  } while (0)

__global__ __launch_bounds__(256) void k_gemm2(
    const ushort* __restrict__ xbf, const ushort* __restrict__ inpbf,
    const float* __restrict__ nrmx, const float* __restrict__ nrmi,
    float* __restrict__ eig, double* __restrict__ scal,
    unsigned long long* __restrict__ cnt)
{
  int id = blockIdx.x;
  int b = id & 7;
  int tm = id >> 3;                 // 0..71
  int mode = (tm >= 36) ? 1 : 0;
  int t = tm - mode * 36;           // 0..35 lower-triangle tile
  int bx = 0;
#pragma unroll
  for (int r = 1; r < 8; r++) if (t >= (r * (r + 1)) / 2) bx = r;
  int by = t - (bx * (bx + 1)) / 2;
  bool diag = (bx == by);
  int D = mode ? DII : DXX;
  const ushort* src = (mode ? inpbf : xbf) + (size_t)b * MBS * D;
  const float* nb = (mode ? nrmi : nrmx) + b * MBS;
  int row0 = bx * 64, col0 = by * 64;

  __shared__ ushort As[2][64 * LSTR];
  __shared__ ushort Bs[2][64 * LSTR];
  __shared__ double redd[256];
  __shared__ unsigned redi[256];

  int tid = threadIdx.x;
  int lane = tid & 63, w = tid >> 6;
  int wr = (w >> 1) * 32, wc = (w & 1) * 32;
  int l15 = lane & 15, l4 = lane >> 4;

  f32x4 acc00 = {0.f, 0.f, 0.f, 0.f}, acc01 = {0.f, 0.f, 0.f, 0.f};
  f32x4 acc10 = {0.f, 0.f, 0.f, 0.f}, acc11 = {0.f, 0.f, 0.f, 0.f};

  int rr = tid >> 3;            // 0..31
  int cc = (tid & 7) * 8;       // 0..56

  const ushort* srcA0 = src + (size_t)(row0 + rr) * D + cc;
  const ushort* srcA1 = src + (size_t)(row0 + 32 + rr) * D + cc;
  const ushort* srcB0 = src + (size_t)(col0 + rr) * D + cc;
  const ushort* srcB1 = src + (size_t)(col0 + 32 + rr) * D + cc;

  bf16x8 pa0, pa1, pb0, pb1;    // even steps -> buf 0
  bf16x8 qa0, qa1, qb0, qb1;    // odd steps  -> buf 1

  LOAD_SET(pa0, pa1, pb0, pb1, 0);
  LOAD_SET(qa0, qa1, qb0, qb1, 64);

  int nk = D >> 6;              // 128 (x) or 48 (inp), both even
  for (int k = 0; k < nk; k += 2) {
    WRITE_LDS(0, pa0, pa1, pb0, pb1);
    if (k + 2 < nk) LOAD_SET(pa0, pa1, pb0, pb1, (k + 2) << 6);
    LGKM0_BAR;                  // LDS drain only; prefetch stays in flight
    MFMA_PHASE(0);
    WRITE_LDS(1, qa0, qa1, qb0, qb1);
    if (k + 3 < nk) LOAD_SET(qa0, qa1, qb0, qb1, (k + 3) << 6);
    LGKM0_BAR;
    MFMA_PHASE(1);
  }

  // epilogue (C/D layout: col=lane&15, row=(lane>>4)*4+v); mirror off-diag
  float* dst = eig + slotOf(b, mode ? 0 : 1);
  double lsum = 0.0; unsigned lcnt = 0;
#define EPI(ACC, M, N)                                                        \
  do {                                                                        \
    int gr = row0 + wr + (M) * 16 + l4 * 4;                                   \
    int gc = col0 + wc + (N) * 16 + l15;                                      \
    float nj = nb[gc];                                                        \
    _Pragma("unroll")                                                         \
    for (int v = 0; v < 4; v++) {                                             \
      int gi = gr + v;                                                        \
      float d2 = nb[gi] + nj - 2.0f * ACC[v];                                 \
      d2 = fmaxf(d2, 0.0f);                                                   \
      if (gi == gc) d2 = 0.0f;                                                \
      float val;                                                              \
      if (mode == 0) {                                                        \
        val = d2;                                                             \
        if (d2 > 0.0f) { lsum += (double)sqrtf(d2); lcnt++; }                 \
      } else {                                                                \
        val = __expf(-d2 * (1.0f / 64.0f)) * (1.0f / 512.0f);                 \
        lsum += (double)val * val;                                            \
      }                                                                       \
      dst[(size_t)gi * MBS + gc] = val;                                       \
      if (!diag) dst[(size_t)gc * MBS + gi] = val;                            \
    }                                                                         \
  } while (0)
  EPI(acc00, 0, 0); EPI(acc01, 0, 1); EPI(acc10, 1, 0); EPI(acc11, 1, 1);
#undef EPI

  if (!diag) { lsum *= 2.0; lcnt *= 2; }
  __syncthreads();
  redd[tid] = lsum; redi[tid] = lcnt; __syncthreads();
  for (int o = 128; o > 0; o >>= 1) {
    if (tid < o) { redd[tid] += redd[tid + o]; redi[tid] += redi[tid + o]; }
    __syncthreads();
  }
  if (tid == 0) {
    if (mode == 0) {
      atomicAdd(&scal[I_SUMD + b], redd[0]);
      atomicAdd(&cnt[b], (unsigned long long)redi[0]);
    } else {
      atomicAdd(&scal[I_AX2 + b], redd[0]);
    }
  }
}

// ---------------- sigma-search: 25 sigmas/block, fp32 accum ----------------
// grid (32, 2, 8): chunk of 2048 float4, sigma group g (25 sigmas), batch b.
// fp32 per-thread accumulators (static idx), wave shfl reduce, fp64 atomic.
__global__ __launch_bounds__(256) void k_loss(const float* __restrict__ eig,
                                              double* __restrict__ scal,
                                              const unsigned long long* __restrict__ cnt,
                                              unsigned* __restrict__ done) {
  int b = blockIdx.z, g = blockIdx.y;
  double c = (double)cnt[b]; if (c < 1.0) c = 1.0;
  float md = (float)(scal[I_SUMD + b] / c);
  const float4* d2p = (const float4*)(eig + slotOf(b, 1));
  const float4* ayp = (const float4*)(eig + slotOf(b, 2));
  float inv[25], ln[25], ld[25];
#pragma unroll
  for (int i = 0; i < 25; i++) {
    float sg = md * (0.1f + 0.198f * (float)(g * 25 + i));
    inv[i] = 1.0f / (sg * sg);
    ln[i] = 0.0f; ld[i] = 0.0f;
  }
  int base = blockIdx.x * 2048 + threadIdx.x;   // float4 units
#pragma unroll
  for (int l = 0; l < 8; l++) {
    float4 d2v = d2p[base + l * 256];
    float4 ayv = ayp[base + l * 256];
#pragma unroll
    for (int u = 0; u < 4; u++) {
      float d2 = ((const float*)&d2v)[u];
      float ay = ((const float*)&ayv)[u];
#pragma unroll
      for (int i = 0; i < 25; i++) {
        float kk = __expf(-d2 * inv[i]);
        ln[i] = fmaf(kk, ay, ln[i]);     // ky scale (512) folded at atomic
        ld[i] = fmaf(kk, kk, ld[i]);
      }
    }
  }
#pragma unroll
  for (int i = 0; i < 25; i++) {
    float a = ln[i], d = ld[i];
    for (int o = 32; o > 0; o >>= 1) {
      a += __shfl_down(a, o, 64);
      d += __shfl_down(d, o, 64);
    }
    if ((threadIdx.x & 63) == 0) {
      atomicAdd(&scal[I_NUM + b * NSIG + g * 25 + i], (double)a * 512.0);
      atomicAdd(&scal[I_DEN + b * NSIG + g * 25 + i], (double)d);
    }
  }
  __syncthreads();
  if (threadIdx.x == 0) {
    __threadfence();
    unsigned r = atomicAdd(done, 1u);
    if (r == 32 * 2 * NBATCH - 1) {        // last block: sigma chain
      __threadfence();
      double sigma = 0.0;
      for (int bb = 0; bb < NBATCH; bb++) {
        double cc2 = (double)cnt[bb]; if (cc2 < 1.0) cc2 = 1.0;
        double mdd = scal[I_SUMD + bb] / cc2;
        double kyf = sqrt(scal[I_KYF + bb]);
        double best = -1.0; int bi = 0;
        for (int s = 0; s < NSIG; s++) {
          double num = scal[I_NUM + bb * NSIG + s];
          double den = sqrt(scal[I_DEN + bb * NSIG + s]) * kyf;
          double loss = num / den;
          if (loss > best) { best = loss; bi = s; }
        }
        double st = mdd * (0.1 + 0.198 * (double)bi);
        sigma = (bb == 0) ? st : 0.5 * sigma + 0.5 * st;
        scal[I_SIGMA + bb] = sigma;
      }
    }
  }
}

// ---------------- A build + Schur products + off2 fusion ----------------
__global__ __launch_bounds__(256) void k_aj(float* __restrict__ eig,
                                            double* __restrict__ scal) {
  int b = blockIdx.y;
  float sg = (float)scal[I_SIGMA + b];
  float inv = 1.0f / (sg * sg);
  float* A        = eig + slotOf(b, 1);
  const float* AX = eig + slotOf(b, 0);
  const float* AY = eig + slotOf(b, 2);
  float* J1       = eig + slotOf(b, 3);
  float* J2       = eig + slotOf(b, 4);
  double s1 = 0.0, s2 = 0.0, s3 = 0.0;
  size_t base = (size_t)blockIdx.x * 2048 + (size_t)threadIdx.x * 8;
#pragma unroll
  for (int h = 0; h < 2; h++) {
    size_t e = base + h * 4;
    float4 d2v = *(float4*)&A[e];
    float4 axv = *(const float4*)&AX[e];
    float4 ayv = *(const float4*)&AY[e];
    float4 av, j1v, j2v;
#pragma unroll
    for (int u = 0; u < 4; u++) {
      float a = __expf(-((const float*)&d2v)[u] * inv) * (1.0f / 512.0f);
      float j1 = ((const float*)&axv)[u] * a;
      float j2 = a * ((const float*)&ayv)[u];
      ((float*)&av)[u] = a; ((float*)&j1v)[u] = j1; ((float*)&j2v)[u] = j2;
      s1 += (double)a * a; s2 += (double)j1 * j1; s3 += (double)j2 * j2;
    }
    *(float4*)&A[e] = av;
    *(float4*)&J1[e] = j1v;
    *(float4*)&J2[e] = j2v;
  }
  __shared__ double r1[256], r2[256], r3[256];
  r1[threadIdx.x] = s1; r2[threadIdx.x] = s2; r3[threadIdx.x] = s3;
  __syncthreads();
  for (int o = 128; o > 0; o >>= 1) {
    if (threadIdx.x < o) {
      r1[threadIdx.x] += r1[threadIdx.x + o];
      r2[threadIdx.x] += r2[threadIdx.x + o];
      r3[threadIdx.x] += r3[threadIdx.x + o];
    }
    __syncthreads();
  }
  if (threadIdx.x == 0) {
    atomicAdd(&scal[I_A2 + b], r1[0]);
    atomicAdd(&scal[I_JX2 + b], r2[0]);
    atomicAdd(&scal[I_JY2 + b], r3[0]);
  }
}

// ---------------- entropies (closed-form / Jacobi) + fused final ----------------
__global__ __launch_bounds__(512) void k_eigen(float* __restrict__ eig,
                                               double* __restrict__ scal,
                                               unsigned* __restrict__ done,
                                               float* __restrict__ out) {
  int blk = blockIdx.x; int b = blk / 5, m = blk % 5;
  int t = threadIdx.x;
  double off2, scale0;
  if (m == 0)      { off2 = scal[I_AX2 + b] - (1.0 / 512.0);              scale0 = 1.0; }
  else if (m == 1) { off2 = scal[I_A2 + b]  - (1.0 / 512.0);              scale0 = 1.0; }
  else if (m == 2) { off2 = (scal[I_KYF + b] - 512.0) * (1.0 / 262144.0); scale0 = 1.0; }
  else if (m == 3) { off2 = scal[I_JX2 + b] - 7.450580596923828125e-9;    scale0 = 512.0; }
  else             { off2 = scal[I_JY2 + b] - 7.450580596923828125e-9;    scale0 = 512.0; }

  if (off2 * scale0 * scale0 <= 1e-8) {   // entropy err ~739*off2: negligible
    if (t == 0) {
      double diagv = (m >= 3) ? (1.0 / 262144.0) : (1.0 / 512.0);
      double wv = diagv * scale0 + 1e-6;
      scal[I_ENT + b * 5 + m] = -512.0 * wv * log2(wv);
    }
  } else {
    // ---- Jacobi fallback (reads the materialized matrix) ----
    float* M = eig + slotOf(b, m);
    __shared__ double red[512];
    __shared__ float csA[256], csB[256];
    __shared__ int anyrot;
    __shared__ double sh_scale, sh_off2;

    red[t] = (double)M[(size_t)t * 513]; __syncthreads();
    for (int o = 256; o > 0; o >>= 1) { if (t < o) red[t] += red[t + o]; __syncthreads(); }
    if (t == 0) { double trace = red[0]; sh_scale = (m >= 3) ? 1.0 / trace : 1.0; }
    __syncthreads();
    double scale = sh_scale;

    for (int sweep = 0; sweep < 30; sweep++) {
      double c2 = 0.0;
      for (int i = 0; i < 512; i++) {
        if (i != t) { float v = M[(size_t)i * 512 + t]; c2 += (double)v * v; }
      }
      red[t] = c2; __syncthreads();
      for (int o = 256; o > 0; o >>= 1) { if (t < o) red[t] += red[t + o]; __syncthreads(); }
      if (t == 0) sh_off2 = red[0];
      __syncthreads();
      if (sh_off2 * scale * scale <= 1e-8) break;

      for (int r = 0; r < 511; r++) {
        if (t == 0) anyrot = 0;
        __syncthreads();
        if (t < 256) {
          int p, q;
          if (t == 0) { p = 511; q = r; }
          else { p = (r + t) % 511; q = (r + 511 - t) % 511; }
          float app = M[(size_t)p * 512 + p];
          float aqq = M[(size_t)q * 512 + q];
          float apq = M[(size_t)p * 512 + q];
          float c = 1.0f, sr = 0.0f;
          if (fabsf(apq) > 1e-12f) {
            float th = (aqq - app) / (2.0f * apq);
            float tt = ((th >= 0.0f) ? 1.0f : -1.0f) / (fabsf(th) + sqrtf(1.0f + th * th));
            c = 1.0f / sqrtf(1.0f + tt * tt);
            sr = tt * c;
            anyrot = 1;
          }
          csA[t] = c; csB[t] = sr;
        }
        __syncthreads();
        if (anyrot) {
          int pair = t >> 1, half = t & 1;
          float c = csA[pair], sr = csB[pair];
          int p, q;
          if (pair == 0) { p = 511; q = r; }
          else { p = (r + pair) % 511; q = (r + 511 - pair) % 511; }
          if (sr != 0.0f) {
            size_t rp = (size_t)p * 512, rq = (size_t)q * 512;
            int j0 = half * 256;
            for (int j = j0; j < j0 + 256; j++) {
              float xx = M[rp + j], yy = M[rq + j];
              M[rp + j] = c * xx - sr * yy;
              M[rq + j] = sr * xx + c * yy;
            }
          }
          __syncthreads();
          if (sr != 0.0f) {
            int j0 = half * 256;
            for (int j = j0; j < j0 + 256; j++) {
              float xx = M[(size_t)j * 512 + p], yy = M[(size_t)j * 512 + q];
              M[(size_t)j * 512 + p] = c * xx - sr * yy;
              M[(size_t)j * 512 + q] = sr * xx + c * yy;
            }
          }
        }
        __syncthreads();
      }
    }

    double wv = (double)M[(size_t)t * 513] * scale + 1e-6;
    red[t] = -wv * log2(wv); __syncthreads();
    for (int o = 256; o > 0; o >>= 1) { if (t < o) red[t] += red[t + o]; __syncthreads(); }
    if (t == 0) scal[I_ENT + b * 5 + m] = red[0];
  }

  __syncthreads();
  if (t == 0) {
    __threadfence();
    unsigned r = atomicAdd(done, 1u);
    if (r == 39) {                        // last block: MI means
      __threadfence();
      double ixt = 0.0, ity = 0.0;
      for (int bb = 0; bb < NBATCH; bb++) {
        const double* E = &scal[I_ENT + bb * 5];
        ixt += E[0] + E[1] - E[3];
        ity += E[1] + E[2] - E[4];
      }
      out[NTOT]     = (float)(ixt / 8.0);
      out[NTOT + 1] = (float)(ity / 8.0);
    }
  }
}

extern "C" void kernel_launch(void* const* d_in, const int* in_sizes, int n_in,
                              void* d_out, int out_size, void* d_ws, size_t ws_size,
                              hipStream_t stream) {
  const float* x   = (const float*)d_in[0];
  const float* inp = (const float*)d_in[1];
  const float* lab = (const float*)d_in[2];
  float* out = (float*)d_out;

  char* ws = (char*)d_ws;
  double* scal = (double*)ws;                                  // 944 doubles = 7552 B
  unsigned long long* cnt = (unsigned long long*)(ws + 7552);  // 64 B -> 7616
  unsigned* done_loss = (unsigned*)(ws + 7616);                // 4 B
  unsigned* done_eig  = (unsigned*)(ws + 7620);                // 4 B -> 7624
  float* nrmx = (float*)(ws + 7680);                           // 16 KB
  float* nrmi = (float*)(ws + 24064);                          // 16 KB -> 40448

  // Scratch: eig(40MB) + xbf(64MB) + inpbf(24MB) = 134217728 B exactly.
  const size_t EIG_OFF = 65536;
  bool big = ws_size >= EIG_OFF + 134217728ULL;
  char* base = big ? (ws + EIG_OFF) : (char*)d_out;
  float* eig = (float*)base;
  ushort* xbf = (ushort*)(base + 41943040);       // 40*NN*4
  ushort* inpbf = (ushort*)(base + 109051904);    // +4096*8192*2

  hipMemsetAsync(ws, 0, 7624, stream);

  k_prep<<<8192, 256, 0, stream>>>((const float4*)x, (float4*)d_out, big ? 1 : 0,
                                   inp, lab, xbf, inpbf, nrmx, nrmi, eig, scal);
  k_gemm2<<<576, 256, 0, stream>>>(xbf, inpbf, nrmx, nrmi, eig, scal, cnt);
  k_loss<<<dim3(32, 2, NBATCH), 256, 0, stream>>>(eig, scal, cnt, done_loss);
  k_aj<<<dim3(128, NBATCH), 256, 0, stream>>>(eig, scal);
  k_eigen<<<40, 512, 0, stream>>>(eig, scal, done_eig, out);
  if (!big) {
    k_copy<<<2048, 256, 0, stream>>>((const float4*)x, (float4*)d_out, NTOT / 4);
  }
}

// Round 11
// 280.195 us; speedup vs baseline: 14.2999x; 1.0365x over previous
//
#include <hip/hip_runtime.h>
#include <hip/hip_bf16.h>
#include <math.h>

// InformationPlane R11 (= R10 with compile fix): k_prep rebuilt for MLP.
// R9's k_prep ran at 2.8 TB/s with VGPR=32 (~1.5KB in flight/CU; Little's law
// needs ~9KB for 6.3 TB/s). Load all 8 row-float4s into NAMED registers
// before any store; nontemporal stores (via clang ext-vector f32x4 — HIP's
// float4 struct is rejected by the builtin) for the 134MB x-copy.

#define NBATCH 8
#define MBS    512
#define DXX    8192
#define DII    3072
#define NSIG   50
#define NN     262144                 // 512*512
#define NTOT   ((size_t)33554432)     // 4096*8192

// scal (double) indices
#define I_SUMD  0    // 8
#define I_KYF   8    // 8
#define I_SIGMA 24   // 8
#define I_ENT   32   // 40 (b*5+m)
#define I_NUM   96   // 8*50
#define I_DEN   512  // 8*50 -> 912
#define I_AX2   912  // 8  sum ax^2
#define I_A2    920  // 8  sum a^2
#define I_JX2   928  // 8  sum (ax*a)^2
#define I_JY2   936  // 8  sum (a*ay)^2 -> ends 944

typedef __attribute__((ext_vector_type(8))) short bf16x8;
typedef __attribute__((ext_vector_type(4))) float f32x4;

__device__ __forceinline__ size_t slotOf(int b, int m) {
  return ((size_t)(b * 5 + m)) * (size_t)NN;
}

__device__ __forceinline__ short f2b(float f) {
  __hip_bfloat16 h = __float2bfloat16(f);
  return *(short*)&h;
}

__device__ __forceinline__ ushort4 cvt4(float4 a) {
  ushort4 v;
  v.x = (ushort)f2b(a.x); v.y = (ushort)f2b(a.y);
  v.z = (ushort)f2b(a.z); v.w = (ushort)f2b(a.w);
  return v;
}

__device__ __forceinline__ double n4(float4 a) {
  return (double)a.x * a.x + (double)a.y * a.y + (double)a.z * a.z + (double)a.w * a.w;
}

__device__ __forceinline__ void nt_store4(float4 v, float4* p) {
  f32x4 w = {v.x, v.y, v.z, v.w};
  __builtin_nontemporal_store(w, (f32x4*)p);
}

// ---------------- copy x -> out (small-ws path only) ----------------
__global__ void k_copy(const float4* __restrict__ src, float4* __restrict__ dst, size_t n4) {
  size_t i = (size_t)blockIdx.x * blockDim.x + threadIdx.x;
  size_t stride = (size_t)gridDim.x * blockDim.x;
  for (; i < n4; i += stride) dst[i] = src[i];
}

// ---------------- fused prep: x-rows | inp-rows | Ky ----------------
__global__ __launch_bounds__(256) void k_prep(
    const float4* __restrict__ x4, float4* __restrict__ xcopy, int docopy,
    const float* __restrict__ inp, const float* __restrict__ lab,
    ushort* __restrict__ xbf, ushort* __restrict__ inpbf,
    float* __restrict__ nrmx, float* __restrict__ nrmi,
    float* __restrict__ eig, double* __restrict__ scal)
{
  __shared__ double red[256];
  int bid = blockIdx.x, t = threadIdx.x;

  if (bid < 4096) {                       // ---- x rows ----
    int row = bid;
    const float4* p4 = x4 + (size_t)row * 2048;
    // 8 named loads, all issued before any store (MLP)
    float4 f0 = p4[t];
    float4 f1 = p4[t + 256];
    float4 f2 = p4[t + 512];
    float4 f3 = p4[t + 768];
    float4 f4 = p4[t + 1024];
    float4 f5 = p4[t + 1280];
    float4 f6 = p4[t + 1536];
    float4 f7 = p4[t + 1792];
    if (docopy) {
      float4* q4 = xcopy + (size_t)row * 2048;
      nt_store4(f0, q4 + t);
      nt_store4(f1, q4 + t + 256);
      nt_store4(f2, q4 + t + 512);
      nt_store4(f3, q4 + t + 768);
      nt_store4(f4, q4 + t + 1024);
      nt_store4(f5, q4 + t + 1280);
      nt_store4(f6, q4 + t + 1536);
      nt_store4(f7, q4 + t + 1792);
    }
    ushort4* o4 = (ushort4*)(xbf + (size_t)row * 8192);
    o4[t]        = cvt4(f0);
    o4[t + 256]  = cvt4(f1);
    o4[t + 512]  = cvt4(f2);
    o4[t + 768]  = cvt4(f3);
    o4[t + 1024] = cvt4(f4);
    o4[t + 1280] = cvt4(f5);
    o4[t + 1536] = cvt4(f6);
    o4[t + 1792] = cvt4(f7);
    double s = n4(f0) + n4(f1) + n4(f2) + n4(f3) + n4(f4) + n4(f5) + n4(f6) + n4(f7);
    red[t] = s; __syncthreads();
    for (int o2 = 128; o2 > 0; o2 >>= 1) {
      if (t < o2) red[t] += red[t + o2];
      __syncthreads();
    }
    if (t == 0) nrmx[row] = (float)red[0];
    return;
  }

  if (bid < 6144) {                       // ---- inp: 2 rows per block ----
    int p = bid - 4096;                   // row pair
    const float4* src4 = (const float4*)inp + (size_t)p * 768;
    ushort4* dst4 = (ushort4*)inpbf + (size_t)p * 768;
    float4 g0 = src4[t];
    float4 g1 = src4[t + 256];
    float4 g2 = src4[t + 512];
    dst4[t]       = cvt4(g0);
    dst4[t + 256] = cvt4(g1);
    dst4[t + 512] = cvt4(g2);
    double s0 = n4(g0), s1 = n4(g2);      // g0: f=t<384 always row0; g2: f>=512 always row1
    double sm = n4(g1);                   // g1: f=256+t -> row0 iff t<128
    if (t < 128) s0 += sm; else s1 += sm;
    red[t] = s0; __syncthreads();
    for (int o = 128; o > 0; o >>= 1) { if (t < o) red[t] += red[t + o]; __syncthreads(); }
    if (t == 0) nrmi[2 * p] = (float)red[0];
    __syncthreads();
    red[t] = s1; __syncthreads();
    for (int o = 128; o > 0; o >>= 1) { if (t < o) red[t] += red[t + o]; __syncthreads(); }
    if (t == 0) nrmi[2 * p + 1] = (float)red[0];
    return;
  }

  // ---- Ky ----
  int idx = bid - 6144;                   // 0..2047
  int b = idx >> 8, xb = idx & 255;
  int e0 = xb * 1024 + t * 4;
  int i = e0 >> 9;
  const float* L = lab + (size_t)b * MBS * 10;
  float4 out;
  double s = 0.0;
#pragma unroll
  for (int u = 0; u < 4; u++) {
    int j = (e0 & 511) + u;
    float d2 = 0.0f;
#pragma unroll
    for (int d = 0; d < 10; d++) { float dd = L[i * 10 + d] - L[j * 10 + d]; d2 += dd * dd; }
    float ky = __expf(-d2 * 100.0f);
    ((float*)&out)[u] = ky * (1.0f / 512.0f);
    s += (double)ky * ky;
  }
  *(float4*)&eig[slotOf(b, 2) + e0] = out;
  red[t] = s; __syncthreads();
  for (int o = 128; o > 0; o >>= 1) { if (t < o) red[t] += red[t + o]; __syncthreads(); }
  if (t == 0) atomicAdd(&scal[I_KYF + b], red[0]);
}

// ---------------- symmetric bf16-MFMA pdist2 GEMM, 64x64 tiles ----------------
#define LSTR 72
#define LGKM0_BAR                                                             \
  do {                                                                        \
    asm volatile("s_waitcnt lgkmcnt(0)" ::: "memory");                        \
    __builtin_amdgcn_s_barrier();                                             \
    __builtin_amdgcn_sched_barrier(0);                                        \
  } while (0)

#define LOAD_SET(A0, A1, B0, B1, K0)                                          \
  do {                                                                        \
    A0 = *(const bf16x8*)&srcA0[K0];                                          \
    A1 = *(const bf16x8*)&srcA1[K0];                                          \
    B0 = *(const bf16x8*)&srcB0[K0];                                          \
    B1 = *(const bf16x8*)&srcB1[K0];                                          \
  } while (0)

#define WRITE_LDS(BUF, A0, A1, B0, B1)                                        \
  do {                                                                        \
    *(bf16x8*)&As[BUF][rr * LSTR + cc] = A0;                                  \
    *(bf16x8*)&As[BUF][(32 + rr) * LSTR + cc] = A1;                           \
    *(bf16x8*)&Bs[BUF][rr * LSTR + cc] = B0;                                  \
    *(bf16x8*)&Bs[BUF][(32 + rr) * LSTR + cc] = B1;                           \
  } while (0)

#define MFMA_PHASE(BUF)                                                       \
  do {                                                                        \
    _Pragma("unroll")                                                         \
    for (int ks = 0; ks < 2; ks++) {                                          \
      bf16x8 af0 = *(const bf16x8*)&As[BUF][(wr + l15) * LSTR + ks * 32 + l4 * 8];          \
      bf16x8 af1 = *(const bf16x8*)&As[BUF][(wr + 16 + l15) * LSTR + ks * 32 + l4 * 8];     \
      bf16x8 bg0 = *(const bf16x8*)&Bs[BUF][(wc + l15) * LSTR + ks * 32 + l4 * 8];          \
      bf16x8 bg1 = *(const bf16x8*)&Bs[BUF][(wc + 16 + l15) * LSTR + ks * 32 + l4 * 8];     \
      acc00 = __builtin_amdgcn_mfma_f32_16x16x32_bf16(af0, bg0, acc00, 0, 0, 0);            \
      acc01 = __builtin_amdgcn_mfma_f32_16x16x32_bf16(af0, bg1, acc01, 0, 0, 0);            \
      acc10 = __builtin_amdgcn_mfma_f32_16x16x32_bf16(af1, bg0, acc10, 0, 0, 0);            \
      acc11 = __builtin_amdgcn_mfma_f32_16x16x32_bf16(af1, bg1, acc11, 0, 0, 0);            \
    }                                                                         \
  } while (0)

__global__ __launch_bounds__(256) void k_gemm2(
    const ushort* __restrict__ xbf, const ushort* __restrict__ inpbf,
    const float* __restrict__ nrmx, const float* __restrict__ nrmi,
    float* __restrict__ eig, double* __restrict__ scal,
    unsigned long long* __restrict__ cnt)
{
  int id = blockIdx.x;
  int b = id & 7;
  int tm = id >> 3;                 // 0..71
  int mode = (tm >= 36) ? 1 : 0;
  int t = tm - mode * 36;           // 0..35 lower-triangle tile
  int bx = 0;
#pragma unroll
  for (int r = 1; r < 8; r++) if (t >= (r * (r + 1)) / 2) bx = r;
  int by = t - (bx * (bx + 1)) / 2;
  bool diag = (bx == by);
  int D = mode ? DII : DXX;
  const ushort* src = (mode ? inpbf : xbf) + (size_t)b * MBS * D;
  const float* nb = (mode ? nrmi : nrmx) + b * MBS;
  int row0 = bx * 64, col0 = by * 64;

  __shared__ ushort As[2][64 * LSTR];
  __shared__ ushort Bs[2][64 * LSTR];
  __shared__ double redd[256];
  __shared__ unsigned redi[256];

  int tid = threadIdx.x;
  int lane = tid & 63, w = tid >> 6;
  int wr = (w >> 1) * 32, wc = (w & 1) * 32;
  int l15 = lane & 15, l4 = lane >> 4;

  f32x4 acc00 = {0.f, 0.f, 0.f, 0.f}, acc01 = {0.f, 0.f, 0.f, 0.f};
  f32x4 acc10 = {0.f, 0.f, 0.f, 0.f}, acc11 = {0.f, 0.f, 0.f, 0.f};

  int rr = tid >> 3;            // 0..31
  int cc = (tid & 7) * 8;       // 0..56

  const ushort* srcA0 = src + (size_t)(row0 + rr) * D + cc;
  const ushort* srcA1 = src + (size_t)(row0 + 32 + rr) * D + cc;
  const ushort* srcB0 = src + (size_t)(col0 + rr) * D + cc;
  const ushort* srcB1 = src + (size_t)(col0 + 32 + rr) * D + cc;

  bf16x8 pa0, pa1, pb0, pb1;    // even steps -> buf 0
  bf16x8 qa0, qa1, qb0, qb1;    // odd steps  -> buf 1

  LOAD_SET(pa0, pa1, pb0, pb1, 0);
  LOAD_SET(qa0, qa1, qb0, qb1, 64);

  int nk = D >> 6;              // 128 (x) or 48 (inp), both even
  for (int k = 0; k < nk; k += 2) {
    WRITE_LDS(0, pa0, pa1, pb0, pb1);
    if (k + 2 < nk) LOAD_SET(pa0, pa1, pb0, pb1, (k + 2) << 6);
    LGKM0_BAR;                  // LDS drain only; prefetch stays in flight
    MFMA_PHASE(0);
    WRITE_LDS(1, qa0, qa1, qb0, qb1);
    if (k + 3 < nk) LOAD_SET(qa0, qa1, qb0, qb1, (k + 3) << 6);
    LGKM0_BAR;
    MFMA_PHASE(1);
  }

  // epilogue (C/D layout: col=lane&15, row=(lane>>4)*4+v); mirror off-diag
  float* dst = eig + slotOf(b, mode ? 0 : 1);
  double lsum = 0.0; unsigned lcnt = 0;
#define EPI(ACC, M, N)                                                        \
  do {                                                                        \
    int gr = row0 + wr + (M) * 16 + l4 * 4;                                   \
    int gc = col0 + wc + (N) * 16 + l15;                                      \
    float nj = nb[gc];                                                        \
    _Pragma("unroll")                                                         \
    for (int v = 0; v < 4; v++) {                                             \
      int gi = gr + v;                                                        \
      float d2 = nb[gi] + nj - 2.0f * ACC[v];                                 \
      d2 = fmaxf(d2, 0.0f);                                                   \
      if (gi == gc) d2 = 0.0f;                                                \
      float val;                                                              \
      if (mode == 0) {                                                        \
        val = d2;                                                             \
        if (d2 > 0.0f) { lsum += (double)sqrtf(d2); lcnt++; }                 \
      } else {                                                                \
        val = __expf(-d2 * (1.0f / 64.0f)) * (1.0f / 512.0f);                 \
        lsum += (double)val * val;                                            \
      }                                                                       \
      dst[(size_t)gi * MBS + gc] = val;                                       \
      if (!diag) dst[(size_t)gc * MBS + gi] = val;                            \
    }                                                                         \
  } while (0)
  EPI(acc00, 0, 0); EPI(acc01, 0, 1); EPI(acc10, 1, 0); EPI(acc11, 1, 1);
#undef EPI

  if (!diag) { lsum *= 2.0; lcnt *= 2; }
  __syncthreads();
  redd[tid] = lsum; redi[tid] = lcnt; __syncthreads();
  for (int o = 128; o > 0; o >>= 1) {
    if (tid < o) { redd[tid] += redd[tid + o]; redi[tid] += redi[tid + o]; }
    __syncthreads();
  }
  if (tid == 0) {
    if (mode == 0) {
      atomicAdd(&scal[I_SUMD + b], redd[0]);
      atomicAdd(&cnt[b], (unsigned long long)redi[0]);
    } else {
      atomicAdd(&scal[I_AX2 + b], redd[0]);
    }
  }
}

// ---------------- sigma-search: 25 sigmas/block, fp32 accum ----------------
__global__ __launch_bounds__(256) void k_loss(const float* __restrict__ eig,
                                              double* __restrict__ scal,
                                              const unsigned long long* __restrict__ cnt,
                                              unsigned* __restrict__ done) {
  int b = blockIdx.z, g = blockIdx.y;
  double c = (double)cnt[b]; if (c < 1.0) c = 1.0;
  float md = (float)(scal[I_SUMD + b] / c);
  const float4* d2p = (const float4*)(eig + slotOf(b, 1));
  const float4* ayp = (const float4*)(eig + slotOf(b, 2));
  float inv[25], ln[25], ld[25];
#pragma unroll
  for (int i = 0; i < 25; i++) {
    float sg = md * (0.1f + 0.198f * (float)(g * 25 + i));
    inv[i] = 1.0f / (sg * sg);
    ln[i] = 0.0f; ld[i] = 0.0f;
  }
  int base = blockIdx.x * 2048 + threadIdx.x;   // float4 units
#pragma unroll
  for (int l = 0; l < 8; l++) {
    float4 d2v = d2p[base + l * 256];
    float4 ayv = ayp[base + l * 256];
#pragma unroll
    for (int u = 0; u < 4; u++) {
      float d2 = ((const float*)&d2v)[u];
      float ay = ((const float*)&ayv)[u];
#pragma unroll
      for (int i = 0; i < 25; i++) {
        float kk = __expf(-d2 * inv[i]);
        ln[i] = fmaf(kk, ay, ln[i]);     // ky scale (512) folded at atomic
        ld[i] = fmaf(kk, kk, ld[i]);
      }
    }
  }
#pragma unroll
  for (int i = 0; i < 25; i++) {
    float a = ln[i], d = ld[i];
    for (int o = 32; o > 0; o >>= 1) {
      a += __shfl_down(a, o, 64);
      d += __shfl_down(d, o, 64);
    }
    if ((threadIdx.x & 63) == 0) {
      atomicAdd(&scal[I_NUM + b * NSIG + g * 25 + i], (double)a * 512.0);
      atomicAdd(&scal[I_DEN + b * NSIG + g * 25 + i], (double)d);
    }
  }
  __syncthreads();
  if (threadIdx.x == 0) {
    __threadfence();
    unsigned r = atomicAdd(done, 1u);
    if (r == 32 * 2 * NBATCH - 1) {        // last block: sigma chain
      __threadfence();
      double sigma = 0.0;
      for (int bb = 0; bb < NBATCH; bb++) {
        double cc2 = (double)cnt[bb]; if (cc2 < 1.0) cc2 = 1.0;
        double mdd = scal[I_SUMD + bb] / cc2;
        double kyf = sqrt(scal[I_KYF + bb]);
        double best = -1.0; int bi = 0;
        for (int s = 0; s < NSIG; s++) {
          double num = scal[I_NUM + bb * NSIG + s];
          double den = sqrt(scal[I_DEN + bb * NSIG + s]) * kyf;
          double loss = num / den;
          if (loss > best) { best = loss; bi = s; }
        }
        double st = mdd * (0.1 + 0.198 * (double)bi);
        sigma = (bb == 0) ? st : 0.5 * sigma + 0.5 * st;
        scal[I_SIGMA + bb] = sigma;
      }
    }
  }
}

// ---------------- A build + Schur products + off2 fusion ----------------
__global__ __launch_bounds__(256) void k_aj(float* __restrict__ eig,
                                            double* __restrict__ scal) {
  int b = blockIdx.y;
  float sg = (float)scal[I_SIGMA + b];
  float inv = 1.0f / (sg * sg);
  float* A        = eig + slotOf(b, 1);
  const float* AX = eig + slotOf(b, 0);
  const float* AY = eig + slotOf(b, 2);
  float* J1       = eig + slotOf(b, 3);
  float* J2       = eig + slotOf(b, 4);
  double s1 = 0.0, s2 = 0.0, s3 = 0.0;
  size_t base = (size_t)blockIdx.x * 2048 + (size_t)threadIdx.x * 8;
#pragma unroll
  for (int h = 0; h < 2; h++) {
    size_t e = base + h * 4;
    float4 d2v = *(float4*)&A[e];
    float4 axv = *(const float4*)&AX[e];
    float4 ayv = *(const float4*)&AY[e];
    float4 av, j1v, j2v;
#pragma unroll
    for (int u = 0; u < 4; u++) {
      float a = __expf(-((const float*)&d2v)[u] * inv) * (1.0f / 512.0f);
      float j1 = ((const float*)&axv)[u] * a;
      float j2 = a * ((const float*)&ayv)[u];
      ((float*)&av)[u] = a; ((float*)&j1v)[u] = j1; ((float*)&j2v)[u] = j2;
      s1 += (double)a * a; s2 += (double)j1 * j1; s3 += (double)j2 * j2;
    }
    *(float4*)&A[e] = av;
    *(float4*)&J1[e] = j1v;
    *(float4*)&J2[e] = j2v;
  }
  __shared__ double r1[256], r2[256], r3[256];
  r1[threadIdx.x] = s1; r2[threadIdx.x] = s2; r3[threadIdx.x] = s3;
  __syncthreads();
  for (int o = 128; o > 0; o >>= 1) {
    if (threadIdx.x < o) {
      r1[threadIdx.x] += r1[threadIdx.x + o];
      r2[threadIdx.x] += r2[threadIdx.x + o];
      r3[threadIdx.x] += r3[threadIdx.x + o];
    }
    __syncthreads();
  }
  if (threadIdx.x == 0) {
    atomicAdd(&scal[I_A2 + b], r1[0]);
    atomicAdd(&scal[I_JX2 + b], r2[0]);
    atomicAdd(&scal[I_JY2 + b], r3[0]);
  }
}

// ---------------- entropies (closed-form / Jacobi) + fused final ----------------
__global__ __launch_bounds__(512) void k_eigen(float* __restrict__ eig,
                                               double* __restrict__ scal,
                                               unsigned* __restrict__ done,
                                               float* __restrict__ out) {
  int blk = blockIdx.x; int b = blk / 5, m = blk % 5;
  int t = threadIdx.x;
  double off2, scale0;
  if (m == 0)      { off2 = scal[I_AX2 + b] - (1.0 / 512.0);              scale0 = 1.0; }
  else if (m == 1) { off2 = scal[I_A2 + b]  - (1.0 / 512.0);              scale0 = 1.0; }
  else if (m == 2) { off2 = (scal[I_KYF + b] - 512.0) * (1.0 / 262144.0); scale0 = 1.0; }
  else if (m == 3) { off2 = scal[I_JX2 + b] - 7.450580596923828125e-9;    scale0 = 512.0; }
  else             { off2 = scal[I_JY2 + b] - 7.450580596923828125e-9;    scale0 = 512.0; }

  if (off2 * scale0 * scale0 <= 1e-8) {   // entropy err ~739*off2: negligible
    if (t == 0) {
      double diagv = (m >= 3) ? (1.0 / 262144.0) : (1.0 / 512.0);
      double wv = diagv * scale0 + 1e-6;
      scal[I_ENT + b * 5 + m] = -512.0 * wv * log2(wv);
    }
  } else {
    // ---- Jacobi fallback (reads the materialized matrix) ----
    float* M = eig + slotOf(b, m);
    __shared__ double red[512];
    __shared__ float csA[256], csB[256];
    __shared__ int anyrot;
    __shared__ double sh_scale, sh_off2;

    red[t] = (double)M[(size_t)t * 513]; __syncthreads();
    for (int o = 256; o > 0; o >>= 1) { if (t < o) red[t] += red[t + o]; __syncthreads(); }
    if (t == 0) { double trace = red[0]; sh_scale = (m >= 3) ? 1.0 / trace : 1.0; }
    __syncthreads();
    double scale = sh_scale;

    for (int sweep = 0; sweep < 30; sweep++) {
      double c2 = 0.0;
      for (int i = 0; i < 512; i++) {
        if (i != t) { float v = M[(size_t)i * 512 + t]; c2 += (double)v * v; }
      }
      red[t] = c2; __syncthreads();
      for (int o = 256; o > 0; o >>= 1) { if (t < o) red[t] += red[t + o]; __syncthreads(); }
      if (t == 0) sh_off2 = red[0];
      __syncthreads();
      if (sh_off2 * scale * scale <= 1e-8) break;

      for (int r = 0; r < 511; r++) {
        if (t == 0) anyrot = 0;
        __syncthreads();
        if (t < 256) {
          int p, q;
          if (t == 0) { p = 511; q = r; }
          else { p = (r + t) % 511; q = (r + 511 - t) % 511; }
          float app = M[(size_t)p * 512 + p];
          float aqq = M[(size_t)q * 512 + q];
          float apq = M[(size_t)p * 512 + q];
          float c = 1.0f, sr = 0.0f;
          if (fabsf(apq) > 1e-12f) {
            float th = (aqq - app) / (2.0f * apq);
            float tt = ((th >= 0.0f) ? 1.0f : -1.0f) / (fabsf(th) + sqrtf(1.0f + th * th));
            c = 1.0f / sqrtf(1.0f + tt * tt);
            sr = tt * c;
            anyrot = 1;
          }
          csA[t] = c; csB[t] = sr;
        }
        __syncthreads();
        if (anyrot) {
          int pair = t >> 1, half = t & 1;
          float c = csA[pair], sr = csB[pair];
          int p, q;
          if (pair == 0) { p = 511; q = r; }
          else { p = (r + pair) % 511; q = (r + 511 - pair) % 511; }
          if (sr != 0.0f) {
            size_t rp = (size_t)p * 512, rq = (size_t)q * 512;
            int j0 = half * 256;
            for (int j = j0; j < j0 + 256; j++) {
              float xx = M[rp + j], yy = M[rq + j];
              M[rp + j] = c * xx - sr * yy;
              M[rq + j] = sr * xx + c * yy;
            }
          }
          __syncthreads();
          if (sr != 0.0f) {
            int j0 = half * 256;
            for (int j = j0; j < j0 + 256; j++) {
              float xx = M[(size_t)j * 512 + p], yy = M[(size_t)j * 512 + q];
              M[(size_t)j * 512 + p] = c * xx - sr * yy;
              M[(size_t)j * 512 + q] = sr * xx + c * yy;
            }
          }
        }
        __syncthreads();
      }
    }

    double wv = (double)M[(size_t)t * 513] * scale + 1e-6;
    red[t] = -wv * log2(wv); __syncthreads();
    for (int o = 256; o > 0; o >>= 1) { if (t < o) red[t] += red[t + o]; __syncthreads(); }
    if (t == 0) scal[I_ENT + b * 5 + m] = red[0];
  }

  __syncthreads();
  if (t == 0) {
    __threadfence();
    unsigned r = atomicAdd(done, 1u);
    if (r == 39) {                        // last block: MI means
      __threadfence();
      double ixt = 0.0, ity = 0.0;
      for (int bb = 0; bb < NBATCH; bb++) {
        const double* E = &scal[I_ENT + bb * 5];
        ixt += E[0] + E[1] - E[3];
        ity += E[1] + E[2] - E[4];
      }
      out[NTOT]     = (float)(ixt / 8.0);
      out[NTOT + 1] = (float)(ity / 8.0);
    }
  }
}

extern "C" void kernel_launch(void* const* d_in, const int* in_sizes, int n_in,
                              void* d_out, int out_size, void* d_ws, size_t ws_size,
                              hipStream_t stream) {
  const float* x   = (const float*)d_in[0];
  const float* inp = (const float*)d_in[1];
  const float* lab = (const float*)d_in[2];
  float* out = (float*)d_out;

  char* ws = (char*)d_ws;
  double* scal = (double*)ws;                                  // 944 doubles = 7552 B
  unsigned long long* cnt = (unsigned long long*)(ws + 7552);  // 64 B -> 7616
  unsigned* done_loss = (unsigned*)(ws + 7616);                // 4 B
  unsigned* done_eig  = (unsigned*)(ws + 7620);                // 4 B -> 7624
  float* nrmx = (float*)(ws + 7680);                           // 16 KB
  float* nrmi = (float*)(ws + 24064);                          // 16 KB -> 40448

  // Scratch: eig(40MB) + xbf(64MB) + inpbf(24MB) = 134217728 B exactly.
  const size_t EIG_OFF = 65536;
  bool big = ws_size >= EIG_OFF + 134217728ULL;
  char* base = big ? (ws + EIG_OFF) : (char*)d_out;
  float* eig = (float*)base;
  ushort* xbf = (ushort*)(base + 41943040);       // 40*NN*4
  ushort* inpbf = (ushort*)(base + 109051904);    // +4096*8192*2

  hipMemsetAsync(ws, 0, 7624, stream);

  k_prep<<<8192, 256, 0, stream>>>((const float4*)x, (float4*)d_out, big ? 1 : 0,
                                   inp, lab, xbf, inpbf, nrmx, nrmi, eig, scal);
  k_gemm2<<<576, 256, 0, stream>>>(xbf, inpbf, nrmx, nrmi, eig, scal, cnt);
  k_loss<<<dim3(32, 2, NBATCH), 256, 0, stream>>>(eig, scal, cnt, done_loss);
  k_aj<<<dim3(128, NBATCH), 256, 0, stream>>>(eig, scal);
  k_eigen<<<40, 512, 0, stream>>>(eig, scal, done_eig, out);
  if (!big) {
    k_copy<<<2048, 256, 0, stream>>>((const float4*)x, (float4*)d_out, NTOT / 4);
  }
}